// Round 1
// baseline (783.544 us; speedup 1.0000x reference)
//
#include <hip/hip_runtime.h>
#include <hip/hip_bf16.h>
#include <math.h>

// Problem constants (match reference setup_inputs()).
#define N_NODES 20000
#define N_EDGES 320000
#define N_GRAPHS 64
#define SEQ 20
#define SCALAR 16
#define EMB 32
#define HID 128
#define IN_DIM 176         // SCALAR + 5*EMB
#define TOT_EDGES (N_EDGES + N_NODES)  // with self loops

// ---------------------------------------------------------------------------
// Kernel 1: feats = concat(scalar, 5x masked-mean-embed) ; LayerNorm -> h
// One block per node, 192 threads (176 used for features).
// ---------------------------------------------------------------------------
__global__ __launch_bounds__(192) void feats_ln_kernel(
    const float* __restrict__ xs,
    const int* __restrict__ i0, const int* __restrict__ i1,
    const int* __restrict__ i2, const int* __restrict__ i3,
    const int* __restrict__ i4,
    const float* __restrict__ t0, const float* __restrict__ t1,
    const float* __restrict__ t2, const float* __restrict__ t3,
    const float* __restrict__ t4,
    const float* __restrict__ gamma, const float* __restrict__ beta,
    float* __restrict__ hout) {
  int n = blockIdx.x, t = threadIdx.x;
  __shared__ int sidx[5][SEQ];
  __shared__ float sf[IN_DIM];
  __shared__ float s_mu, s_rstd;
  if (t < 5 * SEQ) {
    int tab = t / SEQ, l = t % SEQ;
    const int* ip = tab == 0 ? i0 : tab == 1 ? i1 : tab == 2 ? i2 : tab == 3 ? i3 : i4;
    sidx[tab][l] = ip[n * SEQ + l];
  }
  __syncthreads();
  float f = 0.f;
  if (t < SCALAR) {
    f = xs[n * SCALAR + t];
  } else if (t < IN_DIM) {
    int tt = t - SCALAR, tab = tt >> 5, d = tt & 31;
    const float* tp = tab == 0 ? t0 : tab == 1 ? t1 : tab == 2 ? t2 : tab == 3 ? t3 : t4;
    float sum = 0.f, cnt = 0.f;
#pragma unroll
    for (int l = 0; l < SEQ; ++l) {
      int id = sidx[tab][l];
      if (id != 0) { sum += tp[id * EMB + d]; cnt += 1.f; }
    }
    f = sum / (cnt + 1e-9f);
  }
  if (t < IN_DIM) sf[t] = f;
  __syncthreads();
  if (t < 64) {
    float s = 0.f;
    for (int i = t; i < IN_DIM; i += 64) s += sf[i];
    for (int off = 32; off; off >>= 1) s += __shfl_down(s, off);
    if (t == 0) s_mu = s / (float)IN_DIM;
  }
  __syncthreads();
  float mu = s_mu;
  if (t < 64) {
    float s = 0.f;
    for (int i = t; i < IN_DIM; i += 64) { float d2 = sf[i] - mu; s += d2 * d2; }
    for (int off = 32; off; off >>= 1) s += __shfl_down(s, off);
    if (t == 0) s_rstd = 1.0f / sqrtf(s / (float)IN_DIM + 1e-5f);
  }
  __syncthreads();
  if (t < IN_DIM) hout[n * IN_DIM + t] = (f - mu) * s_rstd * gamma[t] + beta[t];
}

// ---------------------------------------------------------------------------
// CSR build: counts, exclusive scan, scatter. Self-loops appended (PyG GAT).
// edge_index flat layout: [0..E) = src row, [E..2E) = dst row.
// ---------------------------------------------------------------------------
__global__ void count_kernel(const int* __restrict__ edge_index,
                             int* __restrict__ cnt, int E, int N) {
  int i = blockIdx.x * blockDim.x + threadIdx.x;
  if (i < E) {
    atomicAdd(&cnt[edge_index[E + i]], 1);
  } else if (i < E + N) {
    atomicAdd(&cnt[i - E], 1);  // self loop dst = node
  }
}

__global__ __launch_bounds__(256) void prefix_kernel(const int* __restrict__ cnt,
                                                     int* __restrict__ indptr,
                                                     int n, int total) {
  __shared__ int ssum[256];
  int t = threadIdx.x;
  int per = (n + 255) / 256;
  int beg = t * per, end = min(beg + per, n);
  int s = 0;
  for (int i = beg; i < end; ++i) s += cnt[i];
  ssum[t] = s;
  __syncthreads();
  if (t == 0) {
    int run = 0;
    for (int i = 0; i < 256; ++i) { int v = ssum[i]; ssum[i] = run; run += v; }
  }
  __syncthreads();
  int run = ssum[t];
  for (int i = beg; i < end; ++i) { indptr[i] = run; run += cnt[i]; }
  if (t == 0) indptr[n] = total;
}

__global__ void scatter_kernel(const int* __restrict__ edge_index,
                               const int* __restrict__ indptr,
                               int* __restrict__ cursor,
                               int* __restrict__ srcs, int E, int N) {
  int i = blockIdx.x * blockDim.x + threadIdx.x;
  int s, d;
  if (i < E) { s = edge_index[i]; d = edge_index[E + i]; }
  else if (i < E + N) { s = i - E; d = s; }
  else return;
  int pos = indptr[d] + atomicAdd(&cursor[d], 1);
  srcs[pos] = s;
}

// ---------------------------------------------------------------------------
// Generic fp32 GEMM: C[M,N] = A[M,K] @ B[K,N]. 64x64 tile, 256 thr, 4x4 micro.
// ---------------------------------------------------------------------------
#define BM 64
#define BN 64
#define BK 16
__global__ __launch_bounds__(256) void gemm_kernel(const float* __restrict__ A,
                                                   const float* __restrict__ B,
                                                   float* __restrict__ C,
                                                   int M, int N, int K) {
  __shared__ float As[BK][BM + 1];
  __shared__ float Bs[BK][BN];
  int bx = blockIdx.x, by = blockIdx.y;
  int tid = threadIdx.x;
  int tcol = tid % 16, trow = tid / 16;
  int row0 = by * BM, col0 = bx * BN;
  float acc[4][4] = {};
  for (int k0 = 0; k0 < K; k0 += BK) {
    for (int i = tid; i < BM * BK; i += 256) {
      int kk = i % BK, r = i / BK;
      int gr = row0 + r, gk = k0 + kk;
      As[kk][r] = (gr < M && gk < K) ? A[gr * K + gk] : 0.f;
    }
    for (int i = tid; i < BK * BN; i += 256) {
      int c = i % BN, kk = i / BN;
      int gc = col0 + c, gk = k0 + kk;
      Bs[kk][c] = (gk < K && gc < N) ? B[gk * N + gc] : 0.f;
    }
    __syncthreads();
#pragma unroll
    for (int kk = 0; kk < BK; ++kk) {
      float a[4], b[4];
#pragma unroll
      for (int i = 0; i < 4; ++i) a[i] = As[kk][trow * 4 + i];
#pragma unroll
      for (int j = 0; j < 4; ++j) b[j] = Bs[kk][tcol * 4 + j];
#pragma unroll
      for (int i = 0; i < 4; ++i)
#pragma unroll
        for (int j = 0; j < 4; ++j) acc[i][j] += a[i] * b[j];
    }
    __syncthreads();
  }
  for (int i = 0; i < 4; ++i) {
    int gr = row0 + trow * 4 + i;
    if (gr >= M) break;
    for (int j = 0; j < 4; ++j) {
      int gc = col0 + tcol * 4 + j;
      if (gc < N) C[gr * N + gc] = acc[i][j];
    }
  }
}

// ---------------------------------------------------------------------------
// Attention coefficients: a_src[n,h] = sum_c xw[n,h,c]*att_src[h,c] (same dst)
// One block per node, H*C threads.
// ---------------------------------------------------------------------------
__global__ void att_kernel(const float* __restrict__ xw,
                           const float* __restrict__ att_src,
                           const float* __restrict__ att_dst,
                           float* __restrict__ a_src, float* __restrict__ a_dst,
                           int H, int C) {
  int n = blockIdx.x, t = threadIdx.x;
  int HC = H * C;
  __shared__ float ss[8], sd[8];
  if (t < H) { ss[t] = 0.f; sd[t] = 0.f; }
  __syncthreads();
  float v = xw[n * HC + t];
  float ps = v * att_src[t], pd = v * att_dst[t];
  for (int off = 32; off; off >>= 1) {
    ps += __shfl_down(ps, off);
    pd += __shfl_down(pd, off);
  }
  if ((t & 63) == 0) {
    int h = t / C;
    atomicAdd(&ss[h], ps);
    atomicAdd(&sd[h], pd);
  }
  __syncthreads();
  if (t < H) {
    a_src[n * H + t] = ss[t];
    a_dst[n * H + t] = sd[t];
  }
}

// ---------------------------------------------------------------------------
// GAT softmax + aggregate per dst node (CSR, no atomics) + bias + ELU.
// Block per dst node, H*C threads. Wave 0 computes per-head max & denom.
// ---------------------------------------------------------------------------
template <int H, int C>
__global__ __launch_bounds__(H * C) void agg_kernel(
    const float* __restrict__ xw, const float* __restrict__ a_src,
    const float* __restrict__ a_dst, const int* __restrict__ indptr,
    const int* __restrict__ srcs, const float* __restrict__ bias,
    float* __restrict__ out) {
  const int HC = H * C;
  int n = blockIdx.x, t = threadIdx.x;
  __shared__ float s_adst[H], s_emax[H], s_denom[H];
  if (t < H) s_adst[t] = a_dst[n * H + t];
  __syncthreads();
  int beg = indptr[n], end = indptr[n + 1];
  if (t < 64) {
    float m[H];
#pragma unroll
    for (int h = 0; h < H; ++h) m[h] = -INFINITY;
    for (int j = beg + t; j < end; j += 64) {
      int s = srcs[j];
#pragma unroll
      for (int h = 0; h < H; ++h) {
        float e = a_src[s * H + h] + s_adst[h];
        e = e >= 0.f ? e : 0.2f * e;
        m[h] = fmaxf(m[h], e);
      }
    }
#pragma unroll
    for (int h = 0; h < H; ++h) {
      for (int off = 32; off; off >>= 1) m[h] = fmaxf(m[h], __shfl_down(m[h], off));
      m[h] = __shfl(m[h], 0);
    }
    float sm[H];
#pragma unroll
    for (int h = 0; h < H; ++h) sm[h] = 0.f;
    for (int j = beg + t; j < end; j += 64) {
      int s = srcs[j];
#pragma unroll
      for (int h = 0; h < H; ++h) {
        float e = a_src[s * H + h] + s_adst[h];
        e = e >= 0.f ? e : 0.2f * e;
        sm[h] += expf(e - m[h]);
      }
    }
#pragma unroll
    for (int h = 0; h < H; ++h) {
      for (int off = 32; off; off >>= 1) sm[h] += __shfl_down(sm[h], off);
    }
    if (t == 0) {
#pragma unroll
      for (int h = 0; h < H; ++h) {
        s_emax[h] = m[h];
        s_denom[h] = sm[h] + 1e-16f;
      }
    }
  }
  __syncthreads();
  int h = t / C;
  float adh = s_adst[h], em = s_emax[h], dn = s_denom[h];
  float acc = 0.f;
  for (int j = beg; j < end; ++j) {
    int s = srcs[j];
    float e = a_src[s * H + h] + adh;
    e = e >= 0.f ? e : 0.2f * e;
    float alpha = expf(e - em) / dn;
    acc += alpha * xw[s * HC + t];
  }
  float v = acc + bias[t];
  out[n * HC + t] = v > 0.f ? v : expf(v) - 1.f;
}

// ---------------------------------------------------------------------------
// Graph ranges (batch is sorted), max-pool per graph, classifier head.
// ---------------------------------------------------------------------------
__global__ void gstart_kernel(const int* __restrict__ batch,
                              int* __restrict__ gstarts, int N, int G) {
  int t = threadIdx.x;
  if (t > G) return;
  int lo = 0, hi = N;
  while (lo < hi) {
    int mid = (lo + hi) >> 1;
    if (batch[mid] < t) lo = mid + 1; else hi = mid;
  }
  gstarts[t] = lo;
}

__global__ __launch_bounds__(HID) void pool_kernel(const float* __restrict__ out2,
                                                   const int* __restrict__ gstarts,
                                                   float* __restrict__ pooled) {
  int g = blockIdx.x, t = threadIdx.x;
  int beg = gstarts[g], end = gstarts[g + 1];
  float m = -INFINITY;
  for (int n = beg; n < end; ++n) m = fmaxf(m, out2[n * HID + t]);
  pooled[g * HID + t] = m;
}

__global__ __launch_bounds__(HID) void cls_kernel(const float* __restrict__ pooled,
                                                  const float* __restrict__ w1,
                                                  const float* __restrict__ b1,
                                                  const float* __restrict__ w2,
                                                  const float* __restrict__ b2,
                                                  float* __restrict__ out) {
  int g = blockIdx.x, t = threadIdx.x;
  __shared__ float sp[HID], sh1[HID / 2];
  sp[t] = pooled[g * HID + t];
  __syncthreads();
  if (t < HID / 2) {
    float s = b1[t];
    for (int k = 0; k < HID; ++k) s += sp[k] * w1[k * (HID / 2) + t];
    sh1[t] = fmaxf(s, 0.f);
  }
  __syncthreads();
  if (t < 2) {
    float o = b2[t];
    for (int k = 0; k < HID / 2; ++k) o += sh1[k] * w2[k * 2 + t];
    out[g * 2 + t] = o;
  }
}

// ---------------------------------------------------------------------------
extern "C" void kernel_launch(void* const* d_in, const int* in_sizes, int n_in,
                              void* d_out, int out_size, void* d_ws, size_t ws_size,
                              hipStream_t stream) {
  const float* x_scalar = (const float*)d_in[0];
  const int* x_opcode   = (const int*)d_in[1];
  const int* x_source   = (const int*)d_in[2];
  const int* x_sink     = (const int*)d_in[3];
  const int* x_string   = (const int*)d_in[4];
  const int* x_payload  = (const int*)d_in[5];
  const int* edge_index = (const int*)d_in[6];
  const int* batch      = (const int*)d_in[7];
  const float* emb_opcode = (const float*)d_in[8];
  const float* emb_source = (const float*)d_in[9];
  const float* emb_sink   = (const float*)d_in[10];
  const float* emb_string = (const float*)d_in[11];
  const float* emb_payload= (const float*)d_in[12];
  const float* ln_gamma = (const float*)d_in[13];
  const float* ln_beta  = (const float*)d_in[14];
  const float* W1       = (const float*)d_in[15];
  const float* att_src1 = (const float*)d_in[16];
  const float* att_dst1 = (const float*)d_in[17];
  const float* b1       = (const float*)d_in[18];
  const float* W2       = (const float*)d_in[19];
  const float* att_src2 = (const float*)d_in[20];
  const float* att_dst2 = (const float*)d_in[21];
  const float* b2       = (const float*)d_in[22];
  const float* cls_w1   = (const float*)d_in[23];
  const float* cls_b1   = (const float*)d_in[24];
  const float* cls_w2   = (const float*)d_in[25];
  const float* cls_b2   = (const float*)d_in[26];

  // Workspace layout (fp32 elements unless noted). ~98.4 MB total.
  float* xw1  = (float*)d_ws;                 // [N, 512]
  float* out1 = xw1 + (size_t)N_NODES * 512;  // [N, 512]
  float* h    = out1 + (size_t)N_NODES * 512; // [N, 176]
  float* xw2  = h;                            // alias: h dead after GEMM1+att1... (GEMM2 writes here)
  float* out2 = xw1;                          // alias: xw1 dead after agg1
  float* a1s  = h + (size_t)N_NODES * IN_DIM; // [N,4]
  float* a1d  = a1s + N_NODES * 4;            // [N,4]
  float* a2s  = a1d + N_NODES * 4;            // [N]
  float* a2d  = a2s + N_NODES;                // [N]
  float* pooled = a2d + N_NODES;              // [G,128]
  int* indptr = (int*)(pooled + N_GRAPHS * HID);  // [N+1]
  int* cnt    = indptr + (N_NODES + 1);       // [N]
  int* cursor = cnt + N_NODES;                // [N]
  int* srcs   = cursor + N_NODES;             // [E+N]
  int* gstarts= srcs + TOT_EDGES;             // [G+1]

  // zero counts + cursors (adjacent)
  hipMemsetAsync(cnt, 0, 2 * N_NODES * sizeof(int), stream);

  feats_ln_kernel<<<N_NODES, 192, 0, stream>>>(
      x_scalar, x_opcode, x_source, x_sink, x_string, x_payload,
      emb_opcode, emb_source, emb_sink, emb_string, emb_payload,
      ln_gamma, ln_beta, h);

  int nthreads = TOT_EDGES;
  count_kernel<<<(nthreads + 255) / 256, 256, 0, stream>>>(edge_index, cnt, N_EDGES, N_NODES);
  prefix_kernel<<<1, 256, 0, stream>>>(cnt, indptr, N_NODES, TOT_EDGES);
  scatter_kernel<<<(nthreads + 255) / 256, 256, 0, stream>>>(edge_index, indptr, cursor, srcs, N_EDGES, N_NODES);

  // GEMM1: [N,176] @ [176,512]
  gemm_kernel<<<dim3(512 / BN, (N_NODES + BM - 1) / BM), 256, 0, stream>>>(
      h, W1, xw1, N_NODES, 512, IN_DIM);
  att_kernel<<<N_NODES, 512, 0, stream>>>(xw1, att_src1, att_dst1, a1s, a1d, 4, HID);
  agg_kernel<4, HID><<<N_NODES, 512, 0, stream>>>(xw1, a1s, a1d, indptr, srcs, b1, out1);

  // GEMM2: [N,512] @ [512,128]
  gemm_kernel<<<dim3(HID / BN, (N_NODES + BM - 1) / BM), 256, 0, stream>>>(
      out1, W2, xw2, N_NODES, HID, 512);
  att_kernel<<<N_NODES, HID, 0, stream>>>(xw2, att_src2, att_dst2, a2s, a2d, 1, HID);
  agg_kernel<1, HID><<<N_NODES, HID, 0, stream>>>(xw2, a2s, a2d, indptr, srcs, b2, out2);

  gstart_kernel<<<1, 128, 0, stream>>>(batch, gstarts, N_NODES, N_GRAPHS);
  pool_kernel<<<N_GRAPHS, HID, 0, stream>>>(out2, gstarts, pooled);
  cls_kernel<<<N_GRAPHS, HID, 0, stream>>>(pooled, cls_w1, cls_b1, cls_w2, cls_b2, (float*)d_out);
}

// Round 2
// 638.692 us; speedup vs baseline: 1.2268x; 1.2268x over previous
//
#include <hip/hip_runtime.h>
#include <hip/hip_bf16.h>
#include <math.h>

// Problem constants (match reference setup_inputs()).
#define N_NODES 20000
#define N_EDGES 320000
#define N_GRAPHS 64
#define SEQ 20
#define SCALAR 16
#define EMB 32
#define HID 128
#define IN_DIM 176         // SCALAR + 5*EMB
#define TOT_EDGES (N_EDGES + N_NODES)  // with self loops

// ---------------------------------------------------------------------------
// Kernel 1: feats = concat(scalar, 5x masked-mean-embed) ; LayerNorm -> h
// ---------------------------------------------------------------------------
__global__ __launch_bounds__(192) void feats_ln_kernel(
    const float* __restrict__ xs,
    const int* __restrict__ i0, const int* __restrict__ i1,
    const int* __restrict__ i2, const int* __restrict__ i3,
    const int* __restrict__ i4,
    const float* __restrict__ t0, const float* __restrict__ t1,
    const float* __restrict__ t2, const float* __restrict__ t3,
    const float* __restrict__ t4,
    const float* __restrict__ gamma, const float* __restrict__ beta,
    float* __restrict__ hout) {
  int n = blockIdx.x, t = threadIdx.x;
  __shared__ int sidx[5][SEQ];
  __shared__ float sf[IN_DIM];
  __shared__ float s_mu, s_rstd;
  if (t < 5 * SEQ) {
    int tab = t / SEQ, l = t % SEQ;
    const int* ip = tab == 0 ? i0 : tab == 1 ? i1 : tab == 2 ? i2 : tab == 3 ? i3 : i4;
    sidx[tab][l] = ip[n * SEQ + l];
  }
  __syncthreads();
  float f = 0.f;
  if (t < SCALAR) {
    f = xs[n * SCALAR + t];
  } else if (t < IN_DIM) {
    int tt = t - SCALAR, tab = tt >> 5, d = tt & 31;
    const float* tp = tab == 0 ? t0 : tab == 1 ? t1 : tab == 2 ? t2 : tab == 3 ? t3 : t4;
    float sum = 0.f, cnt = 0.f;
#pragma unroll
    for (int l = 0; l < SEQ; ++l) {
      int id = sidx[tab][l];
      if (id != 0) { sum += tp[id * EMB + d]; cnt += 1.f; }
    }
    f = sum / (cnt + 1e-9f);
  }
  if (t < IN_DIM) sf[t] = f;
  __syncthreads();
  if (t < 64) {
    float s = 0.f;
    for (int i = t; i < IN_DIM; i += 64) s += sf[i];
    for (int off = 32; off; off >>= 1) s += __shfl_down(s, off);
    if (t == 0) s_mu = s / (float)IN_DIM;
  }
  __syncthreads();
  float mu = s_mu;
  if (t < 64) {
    float s = 0.f;
    for (int i = t; i < IN_DIM; i += 64) { float d2 = sf[i] - mu; s += d2 * d2; }
    for (int off = 32; off; off >>= 1) s += __shfl_down(s, off);
    if (t == 0) s_rstd = 1.0f / sqrtf(s / (float)IN_DIM + 1e-5f);
  }
  __syncthreads();
  if (t < IN_DIM) hout[n * IN_DIM + t] = (f - mu) * s_rstd * gamma[t] + beta[t];
}

// ---------------------------------------------------------------------------
// CSR build: counts, exclusive scan, scatter. Self-loops appended (PyG GAT).
// ---------------------------------------------------------------------------
__global__ void count_kernel(const int* __restrict__ edge_index,
                             int* __restrict__ cnt, int E, int N) {
  int i = blockIdx.x * blockDim.x + threadIdx.x;
  if (i < E) {
    atomicAdd(&cnt[edge_index[E + i]], 1);
  } else if (i < E + N) {
    atomicAdd(&cnt[i - E], 1);  // self loop dst = node
  }
}

__global__ __launch_bounds__(256) void prefix_kernel(const int* __restrict__ cnt,
                                                     int* __restrict__ indptr,
                                                     int n, int total) {
  __shared__ int ssum[256];
  int t = threadIdx.x;
  int per = (n + 255) / 256;
  int beg = t * per, end = min(beg + per, n);
  int s = 0;
  for (int i = beg; i < end; ++i) s += cnt[i];
  ssum[t] = s;
  __syncthreads();
  if (t == 0) {
    int run = 0;
    for (int i = 0; i < 256; ++i) { int v = ssum[i]; ssum[i] = run; run += v; }
  }
  __syncthreads();
  int run = ssum[t];
  for (int i = beg; i < end; ++i) { indptr[i] = run; run += cnt[i]; }
  if (t == 0) indptr[n] = total;
}

__global__ void scatter_kernel(const int* __restrict__ edge_index,
                               const int* __restrict__ indptr,
                               int* __restrict__ cursor,
                               int* __restrict__ srcs, int E, int N) {
  int i = blockIdx.x * blockDim.x + threadIdx.x;
  int s, d;
  if (i < E) { s = edge_index[i]; d = edge_index[E + i]; }
  else if (i < E + N) { s = i - E; d = s; }
  else return;
  int pos = indptr[d] + atomicAdd(&cursor[d], 1);
  srcs[pos] = s;
}

// ---------------------------------------------------------------------------
// fp32 GEMM: C[M,N] = A[M,K] @ B[K,N]. 128xBN tile, BK=8, 256 thr, 8xTN micro.
// Requires K % 8 == 0, N % BN == 0 (true here: K=176/512, N=512/128).
// ---------------------------------------------------------------------------
template <int BN, int TN>
__global__ __launch_bounds__(256) void gemm_kernel(const float* __restrict__ A,
                                                   const float* __restrict__ B,
                                                   float* __restrict__ C,
                                                   int M, int N, int K) {
  const int BM = 128, BK = 8, TM = 8;
  __shared__ float As[BK][BM + 4];  // +4 keeps float4 alignment, breaks stride
  __shared__ float Bs[BK][BN];
  int tid = threadIdx.x;
  int tr = tid / 16, tc = tid % 16;  // 16x16 thread grid
  int row0 = blockIdx.y * BM, col0 = blockIdx.x * BN;
  float acc[TM][TN] = {};
  for (int k0 = 0; k0 < K; k0 += BK) {
    // A tile: BM*BK/4 = 256 float4 loads (one per thread)
    for (int i = tid; i < BM * BK / 4; i += 256) {
      int r = i / (BK / 4), kq = (i % (BK / 4)) * 4;
      int gr = row0 + r;
      float4 v = make_float4(0.f, 0.f, 0.f, 0.f);
      if (gr < M) v = *(const float4*)&A[(size_t)gr * K + k0 + kq];
      As[kq + 0][r] = v.x; As[kq + 1][r] = v.y;
      As[kq + 2][r] = v.z; As[kq + 3][r] = v.w;
    }
    // B tile: BK*BN/4 float4 loads
    for (int i = tid; i < BK * BN / 4; i += 256) {
      int kk = i / (BN / 4), cq = (i % (BN / 4)) * 4;
      *(float4*)&Bs[kk][cq] = *(const float4*)&B[(size_t)(k0 + kk) * N + col0 + cq];
    }
    __syncthreads();
#pragma unroll
    for (int kk = 0; kk < BK; ++kk) {
      float a[TM], b[TN];
#pragma unroll
      for (int i = 0; i < TM; i += 4)
        *(float4*)&a[i] = *(const float4*)&As[kk][tr * TM + i];
#pragma unroll
      for (int j = 0; j < TN; j += 4)
        *(float4*)&b[j] = *(const float4*)&Bs[kk][tc * TN + j];
#pragma unroll
      for (int i = 0; i < TM; ++i)
#pragma unroll
        for (int j = 0; j < TN; ++j) acc[i][j] += a[i] * b[j];
    }
    __syncthreads();
  }
  for (int i = 0; i < TM; ++i) {
    int gr = row0 + tr * TM + i;
    if (gr >= M) continue;
#pragma unroll
    for (int j = 0; j < TN; j += 4)
      *(float4*)&C[(size_t)gr * N + col0 + tc * TN + j] = *(float4*)&acc[i][j];
  }
}

// ---------------------------------------------------------------------------
// Attention coefficients: a_src[n,h] = sum_c xw[n,h,c]*att_src[h,c]
// ---------------------------------------------------------------------------
__global__ void att_kernel(const float* __restrict__ xw,
                           const float* __restrict__ att_src,
                           const float* __restrict__ att_dst,
                           float* __restrict__ a_src, float* __restrict__ a_dst,
                           int H, int C) {
  int n = blockIdx.x, t = threadIdx.x;
  int HC = H * C;
  __shared__ float ss[8], sd[8];
  if (t < H) { ss[t] = 0.f; sd[t] = 0.f; }
  __syncthreads();
  float v = xw[n * HC + t];
  float ps = v * att_src[t], pd = v * att_dst[t];
  for (int off = 32; off; off >>= 1) {
    ps += __shfl_down(ps, off);
    pd += __shfl_down(pd, off);
  }
  if ((t & 63) == 0) {
    int h = t / C;
    atomicAdd(&ss[h], ps);
    atomicAdd(&sd[h], pd);
  }
  __syncthreads();
  if (t < H) {
    a_src[n * H + t] = ss[t];
    a_dst[n * H + t] = sd[t];
  }
}

// ---------------------------------------------------------------------------
// GAT softmax + aggregate per dst node (CSR). Alpha computed ONCE per
// (edge, head) by wave 0 into LDS; channel loop is pure gather-fma.
// ---------------------------------------------------------------------------
template <int H, int C>
__global__ __launch_bounds__(H * C) void agg_kernel(
    const float* __restrict__ xw, const float* __restrict__ a_src,
    const float* __restrict__ a_dst, const int* __restrict__ indptr,
    const int* __restrict__ srcs, const float* __restrict__ bias,
    float* __restrict__ out) {
  const int HC = H * C;
  int n = blockIdx.x, t = threadIdx.x;
  __shared__ float s_adst[H], s_emax[H], s_rden[H];
  __shared__ int s_src[64];
  __shared__ float s_alpha[64][H];
  if (t < H) s_adst[t] = a_dst[n * H + t];
  __syncthreads();
  int beg = indptr[n], end = indptr[n + 1];
  if (t < 64) {
    float m[H], sm[H];
#pragma unroll
    for (int h = 0; h < H; ++h) m[h] = -INFINITY;
    for (int j = beg + t; j < end; j += 64) {
      int s = srcs[j];
#pragma unroll
      for (int h = 0; h < H; ++h) {
        float e = a_src[s * H + h] + s_adst[h];
        e = e >= 0.f ? e : 0.2f * e;
        m[h] = fmaxf(m[h], e);
      }
    }
#pragma unroll
    for (int h = 0; h < H; ++h) {
      for (int off = 32; off; off >>= 1) m[h] = fmaxf(m[h], __shfl_down(m[h], off));
      m[h] = __shfl(m[h], 0);
      sm[h] = 0.f;
    }
    for (int j = beg + t; j < end; j += 64) {
      int s = srcs[j];
#pragma unroll
      for (int h = 0; h < H; ++h) {
        float e = a_src[s * H + h] + s_adst[h];
        e = e >= 0.f ? e : 0.2f * e;
        sm[h] += expf(e - m[h]);
      }
    }
#pragma unroll
    for (int h = 0; h < H; ++h) {
      for (int off = 32; off; off >>= 1) sm[h] += __shfl_down(sm[h], off);
    }
    if (t == 0) {
#pragma unroll
      for (int h = 0; h < H; ++h) {
        s_emax[h] = m[h];
        s_rden[h] = 1.0f / (sm[h] + 1e-16f);
      }
    }
  }
  __syncthreads();
  int h = (H == 1) ? 0 : t / C;
  float acc = 0.f;
  for (int j0 = beg; j0 < end; j0 += 64) {
    int jn = min(64, end - j0);
    if (t < jn) {
      int s = srcs[j0 + t];
      s_src[t] = s;
#pragma unroll
      for (int hh = 0; hh < H; ++hh) {
        float e = a_src[s * H + hh] + s_adst[hh];
        e = e >= 0.f ? e : 0.2f * e;
        s_alpha[t][hh] = expf(e - s_emax[hh]) * s_rden[hh];
      }
    }
    __syncthreads();
    for (int jj = 0; jj < jn; ++jj) {
      acc += s_alpha[jj][h] * xw[(size_t)s_src[jj] * HC + t];
    }
    __syncthreads();
  }
  float v = acc + bias[t];
  out[n * HC + t] = v > 0.f ? v : expf(v) - 1.f;
}

// ---------------------------------------------------------------------------
// Graph ranges (batch is sorted), max-pool per graph, classifier head.
// ---------------------------------------------------------------------------
__global__ void gstart_kernel(const int* __restrict__ batch,
                              int* __restrict__ gstarts, int N, int G) {
  int t = threadIdx.x;
  if (t > G) return;
  int lo = 0, hi = N;
  while (lo < hi) {
    int mid = (lo + hi) >> 1;
    if (batch[mid] < t) lo = mid + 1; else hi = mid;
  }
  gstarts[t] = lo;
}

__global__ __launch_bounds__(HID) void pool_kernel(const float* __restrict__ out2,
                                                   const int* __restrict__ gstarts,
                                                   float* __restrict__ pooled) {
  int g = blockIdx.x, t = threadIdx.x;
  int beg = gstarts[g], end = gstarts[g + 1];
  float m = -INFINITY;
  for (int n = beg; n < end; ++n) m = fmaxf(m, out2[n * HID + t]);
  pooled[g * HID + t] = m;
}

__global__ __launch_bounds__(HID) void cls_kernel(const float* __restrict__ pooled,
                                                  const float* __restrict__ w1,
                                                  const float* __restrict__ b1,
                                                  const float* __restrict__ w2,
                                                  const float* __restrict__ b2,
                                                  float* __restrict__ out) {
  int g = blockIdx.x, t = threadIdx.x;
  __shared__ float sp[HID], sh1[HID / 2];
  sp[t] = pooled[g * HID + t];
  __syncthreads();
  if (t < HID / 2) {
    float s = b1[t];
    for (int k = 0; k < HID; ++k) s += sp[k] * w1[k * (HID / 2) + t];
    sh1[t] = fmaxf(s, 0.f);
  }
  __syncthreads();
  if (t < 2) {
    float o = b2[t];
    for (int k = 0; k < HID / 2; ++k) o += sh1[k] * w2[k * 2 + t];
    out[g * 2 + t] = o;
  }
}

// ---------------------------------------------------------------------------
extern "C" void kernel_launch(void* const* d_in, const int* in_sizes, int n_in,
                              void* d_out, int out_size, void* d_ws, size_t ws_size,
                              hipStream_t stream) {
  const float* x_scalar = (const float*)d_in[0];
  const int* x_opcode   = (const int*)d_in[1];
  const int* x_source   = (const int*)d_in[2];
  const int* x_sink     = (const int*)d_in[3];
  const int* x_string   = (const int*)d_in[4];
  const int* x_payload  = (const int*)d_in[5];
  const int* edge_index = (const int*)d_in[6];
  const int* batch      = (const int*)d_in[7];
  const float* emb_opcode = (const float*)d_in[8];
  const float* emb_source = (const float*)d_in[9];
  const float* emb_sink   = (const float*)d_in[10];
  const float* emb_string = (const float*)d_in[11];
  const float* emb_payload= (const float*)d_in[12];
  const float* ln_gamma = (const float*)d_in[13];
  const float* ln_beta  = (const float*)d_in[14];
  const float* W1       = (const float*)d_in[15];
  const float* att_src1 = (const float*)d_in[16];
  const float* att_dst1 = (const float*)d_in[17];
  const float* b1       = (const float*)d_in[18];
  const float* W2       = (const float*)d_in[19];
  const float* att_src2 = (const float*)d_in[20];
  const float* att_dst2 = (const float*)d_in[21];
  const float* b2       = (const float*)d_in[22];
  const float* cls_w1   = (const float*)d_in[23];
  const float* cls_b1   = (const float*)d_in[24];
  const float* cls_w2   = (const float*)d_in[25];
  const float* cls_b2   = (const float*)d_in[26];

  // Workspace layout (fp32 elements unless noted).
  float* xw1  = (float*)d_ws;                 // [N, 512]
  float* out1 = xw1 + (size_t)N_NODES * 512;  // [N, 512]
  float* h    = out1 + (size_t)N_NODES * 512; // [N, 176]
  float* xw2  = h;                            // alias (h dead after GEMM1)
  float* out2 = xw1;                          // alias (xw1 dead after agg1)
  float* a1s  = h + (size_t)N_NODES * IN_DIM; // [N,4]
  float* a1d  = a1s + N_NODES * 4;
  float* a2s  = a1d + N_NODES * 4;            // [N]
  float* a2d  = a2s + N_NODES;
  float* pooled = a2d + N_NODES;              // [G,128]
  int* indptr = (int*)(pooled + N_GRAPHS * HID);  // [N+1]
  int* cnt    = indptr + (N_NODES + 1);       // [N]
  int* cursor = cnt + N_NODES;                // [N]
  int* srcs   = cursor + N_NODES;             // [E+N]
  int* gstarts= srcs + TOT_EDGES;             // [G+1]

  hipMemsetAsync(cnt, 0, 2 * N_NODES * sizeof(int), stream);

  feats_ln_kernel<<<N_NODES, 192, 0, stream>>>(
      x_scalar, x_opcode, x_source, x_sink, x_string, x_payload,
      emb_opcode, emb_source, emb_sink, emb_string, emb_payload,
      ln_gamma, ln_beta, h);

  int nthreads = TOT_EDGES;
  count_kernel<<<(nthreads + 255) / 256, 256, 0, stream>>>(edge_index, cnt, N_EDGES, N_NODES);
  prefix_kernel<<<1, 256, 0, stream>>>(cnt, indptr, N_NODES, TOT_EDGES);
  scatter_kernel<<<(nthreads + 255) / 256, 256, 0, stream>>>(edge_index, indptr, cursor, srcs, N_EDGES, N_NODES);

  // GEMM1: [N,176] @ [176,512]
  gemm_kernel<128, 8><<<dim3(512 / 128, (N_NODES + 127) / 128), 256, 0, stream>>>(
      h, W1, xw1, N_NODES, 512, IN_DIM);
  att_kernel<<<N_NODES, 512, 0, stream>>>(xw1, att_src1, att_dst1, a1s, a1d, 4, HID);
  agg_kernel<4, HID><<<N_NODES, 512, 0, stream>>>(xw1, a1s, a1d, indptr, srcs, b1, out1);

  // GEMM2: [N,512] @ [512,128]
  gemm_kernel<64, 4><<<dim3(HID / 64, (N_NODES + 127) / 128), 256, 0, stream>>>(
      out1, W2, xw2, N_NODES, HID, 512);
  att_kernel<<<N_NODES, HID, 0, stream>>>(xw2, att_src2, att_dst2, a2s, a2d, 1, HID);
  agg_kernel<1, HID><<<N_NODES, HID, 0, stream>>>(xw2, a2s, a2d, indptr, srcs, b2, out2);

  gstart_kernel<<<1, 128, 0, stream>>>(batch, gstarts, N_NODES, N_GRAPHS);
  pool_kernel<<<N_GRAPHS, HID, 0, stream>>>(out2, gstarts, pooled);
  cls_kernel<<<N_GRAPHS, HID, 0, stream>>>(pooled, cls_w1, cls_b1, cls_w2, cls_b2, (float*)d_out);
}

// Round 3
// 584.480 us; speedup vs baseline: 1.3406x; 1.0928x over previous
//
#include <hip/hip_runtime.h>
#include <hip/hip_bf16.h>
#include <math.h>

// Problem constants (match reference setup_inputs()).
#define N_NODES 20000
#define N_EDGES 320000
#define N_GRAPHS 64
#define SEQ 20
#define SCALAR 16
#define EMB 32
#define HID 128
#define IN_DIM 176         // SCALAR + 5*EMB
#define TOT_EDGES (N_EDGES + N_NODES)  // with self loops

__device__ inline float readlane_f(float v, int l) {
  return __uint_as_float(__builtin_amdgcn_readlane(__float_as_uint(v), l));
}
__device__ inline int readlane_i(int v, int l) {
  return __builtin_amdgcn_readlane(v, l);
}
__device__ inline float leaky(float e) { return e >= 0.f ? e : 0.2f * e; }

// ---------------------------------------------------------------------------
// Kernel 1: feats = concat(scalar, 5x masked-mean-embed) ; LayerNorm -> h
// ---------------------------------------------------------------------------
__global__ __launch_bounds__(192) void feats_ln_kernel(
    const float* __restrict__ xs,
    const int* __restrict__ i0, const int* __restrict__ i1,
    const int* __restrict__ i2, const int* __restrict__ i3,
    const int* __restrict__ i4,
    const float* __restrict__ t0, const float* __restrict__ t1,
    const float* __restrict__ t2, const float* __restrict__ t3,
    const float* __restrict__ t4,
    const float* __restrict__ gamma, const float* __restrict__ beta,
    float* __restrict__ hout) {
  int n = blockIdx.x, t = threadIdx.x;
  __shared__ int sidx[5][SEQ];
  __shared__ float sf[IN_DIM];
  __shared__ float s_mu, s_rstd;
  if (t < 5 * SEQ) {
    int tab = t / SEQ, l = t % SEQ;
    const int* ip = tab == 0 ? i0 : tab == 1 ? i1 : tab == 2 ? i2 : tab == 3 ? i3 : i4;
    sidx[tab][l] = ip[n * SEQ + l];
  }
  __syncthreads();
  float f = 0.f;
  if (t < SCALAR) {
    f = xs[n * SCALAR + t];
  } else if (t < IN_DIM) {
    int tt = t - SCALAR, tab = tt >> 5, d = tt & 31;
    const float* tp = tab == 0 ? t0 : tab == 1 ? t1 : tab == 2 ? t2 : tab == 3 ? t3 : t4;
    float sum = 0.f, cnt = 0.f;
#pragma unroll
    for (int l = 0; l < SEQ; ++l) {
      int id = sidx[tab][l];
      if (id != 0) { sum += tp[id * EMB + d]; cnt += 1.f; }
    }
    f = sum / (cnt + 1e-9f);
  }
  if (t < IN_DIM) sf[t] = f;
  __syncthreads();
  if (t < 64) {
    float s = 0.f;
    for (int i = t; i < IN_DIM; i += 64) s += sf[i];
    for (int off = 32; off; off >>= 1) s += __shfl_down(s, off);
    if (t == 0) s_mu = s / (float)IN_DIM;
  }
  __syncthreads();
  float mu = s_mu;
  if (t < 64) {
    float s = 0.f;
    for (int i = t; i < IN_DIM; i += 64) { float d2 = sf[i] - mu; s += d2 * d2; }
    for (int off = 32; off; off >>= 1) s += __shfl_down(s, off);
    if (t == 0) s_rstd = 1.0f / sqrtf(s / (float)IN_DIM + 1e-5f);
  }
  __syncthreads();
  if (t < IN_DIM) hout[n * IN_DIM + t] = (f - mu) * s_rstd * gamma[t] + beta[t];
}

// ---------------------------------------------------------------------------
// CSR build.
// ---------------------------------------------------------------------------
__global__ void count_kernel(const int* __restrict__ edge_index,
                             int* __restrict__ cnt, int E, int N) {
  int i = blockIdx.x * blockDim.x + threadIdx.x;
  if (i < E) {
    atomicAdd(&cnt[edge_index[E + i]], 1);
  } else if (i < E + N) {
    atomicAdd(&cnt[i - E], 1);  // self loop dst = node
  }
}

__global__ __launch_bounds__(256) void prefix_kernel(const int* __restrict__ cnt,
                                                     int* __restrict__ indptr,
                                                     int n, int total) {
  __shared__ int ssum[256];
  int t = threadIdx.x;
  int per = (n + 255) / 256;
  int beg = t * per, end = min(beg + per, n);
  int s = 0;
  for (int i = beg; i < end; ++i) s += cnt[i];
  ssum[t] = s;
  __syncthreads();
  if (t == 0) {
    int run = 0;
    for (int i = 0; i < 256; ++i) { int v = ssum[i]; ssum[i] = run; run += v; }
  }
  __syncthreads();
  int run = ssum[t];
  for (int i = beg; i < end; ++i) { indptr[i] = run; run += cnt[i]; }
  if (t == 0) indptr[n] = total;
}

__global__ void scatter_kernel(const int* __restrict__ edge_index,
                               const int* __restrict__ indptr,
                               int* __restrict__ cursor,
                               int* __restrict__ srcs, int E, int N) {
  int i = blockIdx.x * blockDim.x + threadIdx.x;
  int s, d;
  if (i < E) { s = edge_index[i]; d = edge_index[E + i]; }
  else if (i < E + N) { s = i - E; d = s; }
  else return;
  int pos = indptr[d] + atomicAdd(&cursor[d], 1);
  srcs[pos] = s;
}

// ---------------------------------------------------------------------------
// fp32 GEMM: C[M,N] = A[M,K] @ B[K,N]. 256 threads (16x16), BK=8.
// ---------------------------------------------------------------------------
template <int BM, int BN, int TM, int TN>
__global__ __launch_bounds__(256) void gemm_kernel(const float* __restrict__ A,
                                                   const float* __restrict__ B,
                                                   float* __restrict__ C,
                                                   int M, int N, int K) {
  const int BK = 8;
  __shared__ float As[BK][BM + 4];
  __shared__ float Bs[BK][BN];
  int tid = threadIdx.x;
  int tr = tid / 16, tc = tid % 16;
  int row0 = blockIdx.y * BM, col0 = blockIdx.x * BN;
  float acc[TM][TN] = {};
  for (int k0 = 0; k0 < K; k0 += BK) {
    for (int i = tid; i < BM * BK / 4; i += 256) {
      int r = i / (BK / 4), kq = (i % (BK / 4)) * 4;
      int gr = row0 + r;
      float4 v = make_float4(0.f, 0.f, 0.f, 0.f);
      if (gr < M) v = *(const float4*)&A[(size_t)gr * K + k0 + kq];
      As[kq + 0][r] = v.x; As[kq + 1][r] = v.y;
      As[kq + 2][r] = v.z; As[kq + 3][r] = v.w;
    }
    for (int i = tid; i < BK * BN / 4; i += 256) {
      int kk = i / (BN / 4), cq = (i % (BN / 4)) * 4;
      *(float4*)&Bs[kk][cq] = *(const float4*)&B[(size_t)(k0 + kk) * N + col0 + cq];
    }
    __syncthreads();
#pragma unroll
    for (int kk = 0; kk < BK; ++kk) {
      float a[TM], b[TN];
#pragma unroll
      for (int i = 0; i < TM; i += 4)
        *(float4*)&a[i] = *(const float4*)&As[kk][tr * TM + i];
#pragma unroll
      for (int j = 0; j < TN; j += 4)
        *(float4*)&b[j] = *(const float4*)&Bs[kk][tc * TN + j];
#pragma unroll
      for (int i = 0; i < TM; ++i)
#pragma unroll
        for (int j = 0; j < TN; ++j) acc[i][j] += a[i] * b[j];
    }
    __syncthreads();
  }
  for (int i = 0; i < TM; ++i) {
    int gr = row0 + tr * TM + i;
    if (gr >= M) continue;
#pragma unroll
    for (int j = 0; j < TN; j += 4)
      *(float4*)&C[(size_t)gr * N + col0 + tc * TN + j] = *(float4*)&acc[i][j];
  }
}

// ---------------------------------------------------------------------------
// Attention coefficients, wave-per-node. Layer 1: H=4, C=128 (row 512).
// ---------------------------------------------------------------------------
__global__ __launch_bounds__(256) void att1_kernel(
    const float* __restrict__ xw, const float* __restrict__ att_s,
    const float* __restrict__ att_d, float* __restrict__ a_s,
    float* __restrict__ a_d) {
  int lane = threadIdx.x & 63;
  int n = blockIdx.x * 4 + (threadIdx.x >> 6);
  if (n >= N_NODES) return;
  const float* r = xw + (size_t)n * 512;
  float4 v0 = *(const float4*)&r[lane * 4];
  float4 v1 = *(const float4*)&r[256 + lane * 4];
  float4 as0 = *(const float4*)&att_s[lane * 4];
  float4 as1 = *(const float4*)&att_s[256 + lane * 4];
  float4 ad0 = *(const float4*)&att_d[lane * 4];
  float4 ad1 = *(const float4*)&att_d[256 + lane * 4];
  float ps0 = v0.x * as0.x + v0.y * as0.y + v0.z * as0.z + v0.w * as0.w;
  float ps1 = v1.x * as1.x + v1.y * as1.y + v1.z * as1.z + v1.w * as1.w;
  float pd0 = v0.x * ad0.x + v0.y * ad0.y + v0.z * ad0.z + v0.w * ad0.w;
  float pd1 = v1.x * ad1.x + v1.y * ad1.y + v1.z * ad1.z + v1.w * ad1.w;
  // reduce within each 32-lane half (channels of one head live in one half)
  for (int off = 1; off < 32; off <<= 1) {
    ps0 += __shfl_xor(ps0, off); ps1 += __shfl_xor(ps1, off);
    pd0 += __shfl_xor(pd0, off); pd1 += __shfl_xor(pd1, off);
  }
  if ((lane & 31) == 0) {
    int h = lane >> 5;  // 0 or 1
    a_s[n * 4 + h] = ps0; a_s[n * 4 + 2 + h] = ps1;
    a_d[n * 4 + h] = pd0; a_d[n * 4 + 2 + h] = pd1;
  }
}

// Layer 2: H=1, C=128.
__global__ __launch_bounds__(256) void att2_kernel(
    const float* __restrict__ xw, const float* __restrict__ att_s,
    const float* __restrict__ att_d, float* __restrict__ a_s,
    float* __restrict__ a_d) {
  int lane = threadIdx.x & 63;
  int n = blockIdx.x * 4 + (threadIdx.x >> 6);
  if (n >= N_NODES) return;
  const float* r = xw + (size_t)n * HID;
  float2 v = *(const float2*)&r[lane * 2];
  float2 as = *(const float2*)&att_s[lane * 2];
  float2 ad = *(const float2*)&att_d[lane * 2];
  float ps = v.x * as.x + v.y * as.y;
  float pd = v.x * ad.x + v.y * ad.y;
  for (int off = 1; off < 64; off <<= 1) {
    ps += __shfl_xor(ps, off);
    pd += __shfl_xor(pd, off);
  }
  if (lane == 0) { a_s[n] = ps; a_d[n] = pd; }
}

// ---------------------------------------------------------------------------
// GAT softmax + aggregate, wave-per-node, zero barriers. Layer 1.
// Lane covers channels [lane*4, lane*4+4) and [256+lane*4, ...+4).
// ---------------------------------------------------------------------------
__global__ __launch_bounds__(256) void agg1_kernel(
    const float* __restrict__ xw, const float* __restrict__ a_src,
    const float* __restrict__ a_dst, const int* __restrict__ indptr,
    const int* __restrict__ srcs, const float* __restrict__ bias,
    float* __restrict__ out) {
  int lane = threadIdx.x & 63;
  int n = blockIdx.x * 4 + (threadIdx.x >> 6);
  if (n >= N_NODES) return;
  int beg = indptr[n], end = indptr[n + 1];
  int deg = end - beg;
  float4 ad = *(const float4*)&a_dst[n * 4];
  float4 acc0 = make_float4(0.f, 0.f, 0.f, 0.f);
  float4 acc1 = make_float4(0.f, 0.f, 0.f, 0.f);
  bool lo = lane < 32;

  auto body = [&](int s, float al0, float al1, float al2, float al3) {
    float a_lo = lo ? al0 : al1;
    float a_hi = lo ? al2 : al3;
    const float* r = xw + (size_t)s * 512;
    float4 v0 = *(const float4*)&r[lane * 4];
    float4 v1 = *(const float4*)&r[256 + lane * 4];
    acc0.x += a_lo * v0.x; acc0.y += a_lo * v0.y;
    acc0.z += a_lo * v0.z; acc0.w += a_lo * v0.w;
    acc1.x += a_hi * v1.x; acc1.y += a_hi * v1.y;
    acc1.z += a_hi * v1.z; acc1.w += a_hi * v1.w;
  };

  if (deg <= 64) {
    // ---- fast path: single chunk, e computed once ----
    int j = beg + lane;
    int s = 0;
    float e0 = -INFINITY, e1 = -INFINITY, e2 = -INFINITY, e3 = -INFINITY;
    if (j < end) {
      s = srcs[j];
      float4 as = *(const float4*)&a_src[s * 4];
      e0 = leaky(as.x + ad.x); e1 = leaky(as.y + ad.y);
      e2 = leaky(as.z + ad.z); e3 = leaky(as.w + ad.w);
    }
    float m0 = e0, m1 = e1, m2 = e2, m3 = e3;
    for (int off = 1; off < 64; off <<= 1) {
      m0 = fmaxf(m0, __shfl_xor(m0, off)); m1 = fmaxf(m1, __shfl_xor(m1, off));
      m2 = fmaxf(m2, __shfl_xor(m2, off)); m3 = fmaxf(m3, __shfl_xor(m3, off));
    }
    float x0 = (j < end) ? expf(e0 - m0) : 0.f;
    float x1 = (j < end) ? expf(e1 - m1) : 0.f;
    float x2 = (j < end) ? expf(e2 - m2) : 0.f;
    float x3 = (j < end) ? expf(e3 - m3) : 0.f;
    float d0 = x0, d1 = x1, d2 = x2, d3 = x3;
    for (int off = 1; off < 64; off <<= 1) {
      d0 += __shfl_xor(d0, off); d1 += __shfl_xor(d1, off);
      d2 += __shfl_xor(d2, off); d3 += __shfl_xor(d3, off);
    }
    float al0 = x0 / (d0 + 1e-16f), al1 = x1 / (d1 + 1e-16f);
    float al2 = x2 / (d2 + 1e-16f), al3 = x3 / (d3 + 1e-16f);
    int jj = 0;
    for (; jj + 2 <= deg; jj += 2) {
      int sa = readlane_i(s, jj), sb = readlane_i(s, jj + 1);
      float a0 = readlane_f(al0, jj), a1 = readlane_f(al1, jj);
      float a2 = readlane_f(al2, jj), a3 = readlane_f(al3, jj);
      float b0 = readlane_f(al0, jj + 1), b1 = readlane_f(al1, jj + 1);
      float b2 = readlane_f(al2, jj + 1), b3 = readlane_f(al3, jj + 1);
      body(sa, a0, a1, a2, a3);
      body(sb, b0, b1, b2, b3);
    }
    if (jj < deg) {
      int sa = readlane_i(s, jj);
      body(sa, readlane_f(al0, jj), readlane_f(al1, jj),
           readlane_f(al2, jj), readlane_f(al3, jj));
    }
  } else {
    // ---- generic path: 3 passes over chunks ----
    float m0 = -INFINITY, m1 = -INFINITY, m2 = -INFINITY, m3 = -INFINITY;
    for (int j0 = beg; j0 < end; j0 += 64) {
      int j = j0 + lane;
      if (j < end) {
        int s = srcs[j];
        float4 as = *(const float4*)&a_src[s * 4];
        m0 = fmaxf(m0, leaky(as.x + ad.x)); m1 = fmaxf(m1, leaky(as.y + ad.y));
        m2 = fmaxf(m2, leaky(as.z + ad.z)); m3 = fmaxf(m3, leaky(as.w + ad.w));
      }
    }
    for (int off = 1; off < 64; off <<= 1) {
      m0 = fmaxf(m0, __shfl_xor(m0, off)); m1 = fmaxf(m1, __shfl_xor(m1, off));
      m2 = fmaxf(m2, __shfl_xor(m2, off)); m3 = fmaxf(m3, __shfl_xor(m3, off));
    }
    float d0 = 0.f, d1 = 0.f, d2 = 0.f, d3 = 0.f;
    for (int j0 = beg; j0 < end; j0 += 64) {
      int j = j0 + lane;
      if (j < end) {
        int s = srcs[j];
        float4 as = *(const float4*)&a_src[s * 4];
        d0 += expf(leaky(as.x + ad.x) - m0); d1 += expf(leaky(as.y + ad.y) - m1);
        d2 += expf(leaky(as.z + ad.z) - m2); d3 += expf(leaky(as.w + ad.w) - m3);
      }
    }
    for (int off = 1; off < 64; off <<= 1) {
      d0 += __shfl_xor(d0, off); d1 += __shfl_xor(d1, off);
      d2 += __shfl_xor(d2, off); d3 += __shfl_xor(d3, off);
    }
    float r0 = 1.f / (d0 + 1e-16f), r1 = 1.f / (d1 + 1e-16f);
    float r2 = 1.f / (d2 + 1e-16f), r3 = 1.f / (d3 + 1e-16f);
    for (int j0 = beg; j0 < end; j0 += 64) {
      int jn = min(64, end - j0);
      int j = j0 + lane;
      int s = 0;
      float al0 = 0.f, al1 = 0.f, al2 = 0.f, al3 = 0.f;
      if (j < end) {
        s = srcs[j];
        float4 as = *(const float4*)&a_src[s * 4];
        al0 = expf(leaky(as.x + ad.x) - m0) * r0;
        al1 = expf(leaky(as.y + ad.y) - m1) * r1;
        al2 = expf(leaky(as.z + ad.z) - m2) * r2;
        al3 = expf(leaky(as.w + ad.w) - m3) * r3;
      }
      for (int jj = 0; jj < jn; ++jj) {
        int sa = readlane_i(s, jj);
        body(sa, readlane_f(al0, jj), readlane_f(al1, jj),
             readlane_f(al2, jj), readlane_f(al3, jj));
      }
    }
  }

  int c0 = lane * 4, c1 = 256 + lane * 4;
  float4 b0 = *(const float4*)&bias[c0];
  float4 b1 = *(const float4*)&bias[c1];
  float4 o0, o1;
  o0.x = acc0.x + b0.x; o0.y = acc0.y + b0.y; o0.z = acc0.z + b0.z; o0.w = acc0.w + b0.w;
  o1.x = acc1.x + b1.x; o1.y = acc1.y + b1.y; o1.z = acc1.z + b1.z; o1.w = acc1.w + b1.w;
  o0.x = o0.x > 0.f ? o0.x : expf(o0.x) - 1.f;
  o0.y = o0.y > 0.f ? o0.y : expf(o0.y) - 1.f;
  o0.z = o0.z > 0.f ? o0.z : expf(o0.z) - 1.f;
  o0.w = o0.w > 0.f ? o0.w : expf(o0.w) - 1.f;
  o1.x = o1.x > 0.f ? o1.x : expf(o1.x) - 1.f;
  o1.y = o1.y > 0.f ? o1.y : expf(o1.y) - 1.f;
  o1.z = o1.z > 0.f ? o1.z : expf(o1.z) - 1.f;
  o1.w = o1.w > 0.f ? o1.w : expf(o1.w) - 1.f;
  *(float4*)&out[(size_t)n * 512 + c0] = o0;
  *(float4*)&out[(size_t)n * 512 + c1] = o1;
}

// ---------------------------------------------------------------------------
// Layer 2 aggregate: H=1, C=128. Lane covers channels [lane*2, lane*2+2).
// ---------------------------------------------------------------------------
__global__ __launch_bounds__(256) void agg2_kernel(
    const float* __restrict__ xw, const float* __restrict__ a_src,
    const float* __restrict__ a_dst, const int* __restrict__ indptr,
    const int* __restrict__ srcs, const float* __restrict__ bias,
    float* __restrict__ out) {
  int lane = threadIdx.x & 63;
  int n = blockIdx.x * 4 + (threadIdx.x >> 6);
  if (n >= N_NODES) return;
  int beg = indptr[n], end = indptr[n + 1];
  int deg = end - beg;
  float adn = a_dst[n];
  float2 acc = make_float2(0.f, 0.f);

  auto body = [&](int s, float al) {
    float2 v = *(const float2*)&xw[(size_t)s * HID + lane * 2];
    acc.x += al * v.x; acc.y += al * v.y;
  };

  if (deg <= 64) {
    int j = beg + lane;
    int s = 0;
    float e = -INFINITY;
    if (j < end) { s = srcs[j]; e = leaky(a_src[s] + adn); }
    float m = e;
    for (int off = 1; off < 64; off <<= 1) m = fmaxf(m, __shfl_xor(m, off));
    float x = (j < end) ? expf(e - m) : 0.f;
    float d = x;
    for (int off = 1; off < 64; off <<= 1) d += __shfl_xor(d, off);
    float al = x / (d + 1e-16f);
    int jj = 0;
    for (; jj + 2 <= deg; jj += 2) {
      int sa = readlane_i(s, jj), sb = readlane_i(s, jj + 1);
      float a0 = readlane_f(al, jj), a1 = readlane_f(al, jj + 1);
      body(sa, a0);
      body(sb, a1);
    }
    if (jj < deg) body(readlane_i(s, jj), readlane_f(al, jj));
  } else {
    float m = -INFINITY;
    for (int j0 = beg; j0 < end; j0 += 64) {
      int j = j0 + lane;
      if (j < end) m = fmaxf(m, leaky(a_src[srcs[j]] + adn));
    }
    for (int off = 1; off < 64; off <<= 1) m = fmaxf(m, __shfl_xor(m, off));
    float d = 0.f;
    for (int j0 = beg; j0 < end; j0 += 64) {
      int j = j0 + lane;
      if (j < end) d += expf(leaky(a_src[srcs[j]] + adn) - m);
    }
    for (int off = 1; off < 64; off <<= 1) d += __shfl_xor(d, off);
    float rd = 1.f / (d + 1e-16f);
    for (int j0 = beg; j0 < end; j0 += 64) {
      int jn = min(64, end - j0);
      int j = j0 + lane;
      int s = 0;
      float al = 0.f;
      if (j < end) {
        s = srcs[j];
        al = expf(leaky(a_src[s] + adn) - m) * rd;
      }
      for (int jj = 0; jj < jn; ++jj)
        body(readlane_i(s, jj), readlane_f(al, jj));
    }
  }

  float2 b = *(const float2*)&bias[lane * 2];
  float2 o;
  o.x = acc.x + b.x; o.y = acc.y + b.y;
  o.x = o.x > 0.f ? o.x : expf(o.x) - 1.f;
  o.y = o.y > 0.f ? o.y : expf(o.y) - 1.f;
  *(float2*)&out[(size_t)n * HID + lane * 2] = o;
}

// ---------------------------------------------------------------------------
// Graph ranges (batch sorted), max-pool per graph, classifier head.
// ---------------------------------------------------------------------------
__global__ void gstart_kernel(const int* __restrict__ batch,
                              int* __restrict__ gstarts, int N, int G) {
  int t = threadIdx.x;
  if (t > G) return;
  int lo = 0, hi = N;
  while (lo < hi) {
    int mid = (lo + hi) >> 1;
    if (batch[mid] < t) lo = mid + 1; else hi = mid;
  }
  gstarts[t] = lo;
}

__global__ __launch_bounds__(HID) void pool_kernel(const float* __restrict__ out2,
                                                   const int* __restrict__ gstarts,
                                                   float* __restrict__ pooled) {
  int g = blockIdx.x, t = threadIdx.x;
  int beg = gstarts[g], end = gstarts[g + 1];
  float m = -INFINITY;
  for (int n = beg; n < end; ++n) m = fmaxf(m, out2[n * HID + t]);
  pooled[g * HID + t] = m;
}

__global__ __launch_bounds__(HID) void cls_kernel(const float* __restrict__ pooled,
                                                  const float* __restrict__ w1,
                                                  const float* __restrict__ b1,
                                                  const float* __restrict__ w2,
                                                  const float* __restrict__ b2,
                                                  float* __restrict__ out) {
  int g = blockIdx.x, t = threadIdx.x;
  __shared__ float sp[HID], sh1[HID / 2];
  sp[t] = pooled[g * HID + t];
  __syncthreads();
  if (t < HID / 2) {
    float s = b1[t];
    for (int k = 0; k < HID; ++k) s += sp[k] * w1[k * (HID / 2) + t];
    sh1[t] = fmaxf(s, 0.f);
  }
  __syncthreads();
  if (t < 2) {
    float o = b2[t];
    for (int k = 0; k < HID / 2; ++k) o += sh1[k] * w2[k * 2 + t];
    out[g * 2 + t] = o;
  }
}

// ---------------------------------------------------------------------------
extern "C" void kernel_launch(void* const* d_in, const int* in_sizes, int n_in,
                              void* d_out, int out_size, void* d_ws, size_t ws_size,
                              hipStream_t stream) {
  const float* x_scalar = (const float*)d_in[0];
  const int* x_opcode   = (const int*)d_in[1];
  const int* x_source   = (const int*)d_in[2];
  const int* x_sink     = (const int*)d_in[3];
  const int* x_string   = (const int*)d_in[4];
  const int* x_payload  = (const int*)d_in[5];
  const int* edge_index = (const int*)d_in[6];
  const int* batch      = (const int*)d_in[7];
  const float* emb_opcode = (const float*)d_in[8];
  const float* emb_source = (const float*)d_in[9];
  const float* emb_sink   = (const float*)d_in[10];
  const float* emb_string = (const float*)d_in[11];
  const float* emb_payload= (const float*)d_in[12];
  const float* ln_gamma = (const float*)d_in[13];
  const float* ln_beta  = (const float*)d_in[14];
  const float* W1       = (const float*)d_in[15];
  const float* att_src1 = (const float*)d_in[16];
  const float* att_dst1 = (const float*)d_in[17];
  const float* b1       = (const float*)d_in[18];
  const float* W2       = (const float*)d_in[19];
  const float* att_src2 = (const float*)d_in[20];
  const float* att_dst2 = (const float*)d_in[21];
  const float* b2       = (const float*)d_in[22];
  const float* cls_w1   = (const float*)d_in[23];
  const float* cls_b1   = (const float*)d_in[24];
  const float* cls_w2   = (const float*)d_in[25];
  const float* cls_b2   = (const float*)d_in[26];

  float* xw1  = (float*)d_ws;                 // [N, 512]
  float* out1 = xw1 + (size_t)N_NODES * 512;  // [N, 512]
  float* h    = out1 + (size_t)N_NODES * 512; // [N, 176]
  float* xw2  = h;                            // alias (h dead after GEMM1)
  float* out2 = xw1;                          // alias (xw1 dead after agg1)
  float* a1s  = h + (size_t)N_NODES * IN_DIM; // [N,4]
  float* a1d  = a1s + N_NODES * 4;
  float* a2s  = a1d + N_NODES * 4;            // [N]
  float* a2d  = a2s + N_NODES;
  float* pooled = a2d + N_NODES;              // [G,128]
  int* indptr = (int*)(pooled + N_GRAPHS * HID);  // [N+1]
  int* cnt    = indptr + (N_NODES + 1);       // [N]
  int* cursor = cnt + N_NODES;                // [N]
  int* srcs   = cursor + N_NODES;             // [E+N]
  int* gstarts= srcs + TOT_EDGES;             // [G+1]

  hipMemsetAsync(cnt, 0, 2 * N_NODES * sizeof(int), stream);

  feats_ln_kernel<<<N_NODES, 192, 0, stream>>>(
      x_scalar, x_opcode, x_source, x_sink, x_string, x_payload,
      emb_opcode, emb_source, emb_sink, emb_string, emb_payload,
      ln_gamma, ln_beta, h);

  int nthreads = TOT_EDGES;
  count_kernel<<<(nthreads + 255) / 256, 256, 0, stream>>>(edge_index, cnt, N_EDGES, N_NODES);
  prefix_kernel<<<1, 256, 0, stream>>>(cnt, indptr, N_NODES, TOT_EDGES);
  scatter_kernel<<<(nthreads + 255) / 256, 256, 0, stream>>>(edge_index, indptr, cursor, srcs, N_EDGES, N_NODES);

  const int NB4 = (N_NODES + 3) / 4;  // wave-per-node grids

  // GEMM1: [N,176] @ [176,512]
  gemm_kernel<128, 128, 8, 8><<<dim3(4, (N_NODES + 127) / 128), 256, 0, stream>>>(
      h, W1, xw1, N_NODES, 512, IN_DIM);
  att1_kernel<<<NB4, 256, 0, stream>>>(xw1, att_src1, att_dst1, a1s, a1d);
  agg1_kernel<<<NB4, 256, 0, stream>>>(xw1, a1s, a1d, indptr, srcs, b1, out1);

  // GEMM2: [N,512] @ [512,128]
  gemm_kernel<64, 128, 4, 8><<<dim3(1, (N_NODES + 63) / 64), 256, 0, stream>>>(
      out1, W2, xw2, N_NODES, HID, 512);
  att2_kernel<<<NB4, 256, 0, stream>>>(xw2, att_src2, att_dst2, a2s, a2d);
  agg2_kernel<<<NB4, 256, 0, stream>>>(xw2, a2s, a2d, indptr, srcs, b2, out2);

  gstart_kernel<<<1, 128, 0, stream>>>(batch, gstarts, N_NODES, N_GRAPHS);
  pool_kernel<<<N_GRAPHS, HID, 0, stream>>>(out2, gstarts, pooled);
  cls_kernel<<<N_GRAPHS, HID, 0, stream>>>(pooled, cls_w1, cls_b1, cls_w2, cls_b2, (float*)d_out);
}

// Round 4
// 577.365 us; speedup vs baseline: 1.3571x; 1.0123x over previous
//
#include <hip/hip_runtime.h>
#include <hip/hip_bf16.h>
#include <math.h>

// Problem constants (match reference setup_inputs()).
#define N_NODES 20000
#define N_EDGES 320000
#define N_GRAPHS 64
#define SEQ 20
#define SCALAR 16
#define EMB 32
#define HID 128
#define IN_DIM 176         // SCALAR + 5*EMB
#define TOT_EDGES (N_EDGES + N_NODES)  // with self loops
#define CHUNK 10000        // node chunk for agg1/gemm_head (workspace bound)

__device__ inline float readlane_f(float v, int l) {
  return __uint_as_float(__builtin_amdgcn_readlane(__float_as_uint(v), l));
}
__device__ inline int readlane_i(int v, int l) {
  return __builtin_amdgcn_readlane(v, l);
}
__device__ inline float leaky(float e) { return e >= 0.f ? e : 0.2f * e; }
__device__ inline float elu(float v) { return v > 0.f ? v : expf(v) - 1.f; }

// ---------------------------------------------------------------------------
// Kernel 1: feats = concat(scalar, 5x masked-mean-embed) ; LayerNorm -> h
// ---------------------------------------------------------------------------
__global__ __launch_bounds__(192) void feats_ln_kernel(
    const float* __restrict__ xs,
    const int* __restrict__ i0, const int* __restrict__ i1,
    const int* __restrict__ i2, const int* __restrict__ i3,
    const int* __restrict__ i4,
    const float* __restrict__ t0, const float* __restrict__ t1,
    const float* __restrict__ t2, const float* __restrict__ t3,
    const float* __restrict__ t4,
    const float* __restrict__ gamma, const float* __restrict__ beta,
    float* __restrict__ hout) {
  int n = blockIdx.x, t = threadIdx.x;
  __shared__ int sidx[5][SEQ];
  __shared__ float sf[IN_DIM];
  __shared__ float s_mu, s_rstd;
  if (t < 5 * SEQ) {
    int tab = t / SEQ, l = t % SEQ;
    const int* ip = tab == 0 ? i0 : tab == 1 ? i1 : tab == 2 ? i2 : tab == 3 ? i3 : i4;
    sidx[tab][l] = ip[n * SEQ + l];
  }
  __syncthreads();
  float f = 0.f;
  if (t < SCALAR) {
    f = xs[n * SCALAR + t];
  } else if (t < IN_DIM) {
    int tt = t - SCALAR, tab = tt >> 5, d = tt & 31;
    const float* tp = tab == 0 ? t0 : tab == 1 ? t1 : tab == 2 ? t2 : tab == 3 ? t3 : t4;
    float sum = 0.f, cnt = 0.f;
#pragma unroll
    for (int l = 0; l < SEQ; ++l) {
      int id = sidx[tab][l];
      if (id != 0) { sum += tp[id * EMB + d]; cnt += 1.f; }
    }
    f = sum / (cnt + 1e-9f);
  }
  if (t < IN_DIM) sf[t] = f;
  __syncthreads();
  if (t < 64) {
    float s = 0.f;
    for (int i = t; i < IN_DIM; i += 64) s += sf[i];
    for (int off = 32; off; off >>= 1) s += __shfl_down(s, off);
    if (t == 0) s_mu = s / (float)IN_DIM;
  }
  __syncthreads();
  float mu = s_mu;
  if (t < 64) {
    float s = 0.f;
    for (int i = t; i < IN_DIM; i += 64) { float d2 = sf[i] - mu; s += d2 * d2; }
    for (int off = 32; off; off >>= 1) s += __shfl_down(s, off);
    if (t == 0) s_rstd = 1.0f / sqrtf(s / (float)IN_DIM + 1e-5f);
  }
  __syncthreads();
  if (t < IN_DIM) hout[n * IN_DIM + t] = (f - mu) * s_rstd * gamma[t] + beta[t];
}

// ---------------------------------------------------------------------------
// CSR build.
// ---------------------------------------------------------------------------
__global__ void count_kernel(const int* __restrict__ edge_index,
                             int* __restrict__ cnt, int E, int N) {
  int i = blockIdx.x * blockDim.x + threadIdx.x;
  if (i < E) {
    atomicAdd(&cnt[edge_index[E + i]], 1);
  } else if (i < E + N) {
    atomicAdd(&cnt[i - E], 1);  // self loop dst = node
  }
}

__global__ __launch_bounds__(256) void prefix_kernel(const int* __restrict__ cnt,
                                                     int* __restrict__ indptr,
                                                     int n, int total) {
  __shared__ int ssum[256];
  int t = threadIdx.x;
  int per = (n + 255) / 256;
  int beg = t * per, end = min(beg + per, n);
  int s = 0;
  for (int i = beg; i < end; ++i) s += cnt[i];
  ssum[t] = s;
  __syncthreads();
  if (t == 0) {
    int run = 0;
    for (int i = 0; i < 256; ++i) { int v = ssum[i]; ssum[i] = run; run += v; }
  }
  __syncthreads();
  int run = ssum[t];
  for (int i = beg; i < end; ++i) { indptr[i] = run; run += cnt[i]; }
  if (t == 0) indptr[n] = total;
}

__global__ void scatter_kernel(const int* __restrict__ edge_index,
                               const int* __restrict__ indptr,
                               int* __restrict__ cursor,
                               int* __restrict__ srcs, int E, int N) {
  int i = blockIdx.x * blockDim.x + threadIdx.x;
  int s, d;
  if (i < E) { s = edge_index[i]; d = edge_index[E + i]; }
  else if (i < E + N) { s = i - E; d = s; }
  else return;
  int pos = indptr[d] + atomicAdd(&cursor[d], 1);
  srcs[pos] = s;
}

// ---------------------------------------------------------------------------
// was/wad precompute: was[k][h] = sum_c W1[k, h*128+c] * att_src1[h*128+c].
// Stored as float4 per k (4 heads). One block.
// ---------------------------------------------------------------------------
__global__ __launch_bounds__(256) void wasd_kernel(
    const float* __restrict__ W1, const float* __restrict__ att_s,
    const float* __restrict__ att_d, float* __restrict__ was4,
    float* __restrict__ wad4) {
  for (int idx = threadIdx.x; idx < IN_DIM * 4; idx += 256) {
    int k = idx >> 2, hh = idx & 3;
    const float* wrow = W1 + (size_t)k * 512 + hh * 128;
    const float* as = att_s + hh * 128;
    const float* ad = att_d + hh * 128;
    float ss = 0.f, sd = 0.f;
    for (int c = 0; c < 128; ++c) { ss += wrow[c] * as[c]; sd += wrow[c] * ad[c]; }
    was4[k * 4 + hh] = ss;
    wad4[k * 4 + hh] = sd;
  }
}

// ---------------------------------------------------------------------------
// Attention logits layer 1 from h: a_src[n,h] = sum_k h[n,k]*was[k,h].
// Wave-per-node (4 nodes / block).
// ---------------------------------------------------------------------------
__global__ __launch_bounds__(256) void att1h_kernel(
    const float* __restrict__ h, const float* __restrict__ was4,
    const float* __restrict__ wad4, float* __restrict__ a_s,
    float* __restrict__ a_d) {
  int lane = threadIdx.x & 63;
  int n = blockIdx.x * 4 + (threadIdx.x >> 6);
  if (n >= N_NODES) return;
  const float* hr = h + (size_t)n * IN_DIM;
  bool l48 = lane < 48;
  float v0 = hr[lane];
  float v1 = hr[64 + lane];
  float v2 = l48 ? hr[128 + lane] : 0.f;
  const float4* wsv = (const float4*)was4;
  const float4* wdv = (const float4*)wad4;
  float4 wsa = wsv[lane], wsb = wsv[64 + lane];
  float4 wsc = l48 ? wsv[128 + lane] : make_float4(0.f, 0.f, 0.f, 0.f);
  float4 wda = wdv[lane], wdb = wdv[64 + lane];
  float4 wdc = l48 ? wdv[128 + lane] : make_float4(0.f, 0.f, 0.f, 0.f);
  float ps0 = v0 * wsa.x + v1 * wsb.x + v2 * wsc.x;
  float ps1 = v0 * wsa.y + v1 * wsb.y + v2 * wsc.y;
  float ps2 = v0 * wsa.z + v1 * wsb.z + v2 * wsc.z;
  float ps3 = v0 * wsa.w + v1 * wsb.w + v2 * wsc.w;
  float pd0 = v0 * wda.x + v1 * wdb.x + v2 * wdc.x;
  float pd1 = v0 * wda.y + v1 * wdb.y + v2 * wdc.y;
  float pd2 = v0 * wda.z + v1 * wdb.z + v2 * wdc.z;
  float pd3 = v0 * wda.w + v1 * wdb.w + v2 * wdc.w;
  for (int off = 1; off < 64; off <<= 1) {
    ps0 += __shfl_xor(ps0, off); ps1 += __shfl_xor(ps1, off);
    ps2 += __shfl_xor(ps2, off); ps3 += __shfl_xor(ps3, off);
    pd0 += __shfl_xor(pd0, off); pd1 += __shfl_xor(pd1, off);
    pd2 += __shfl_xor(pd2, off); pd3 += __shfl_xor(pd3, off);
  }
  if (lane == 0) {
    *(float4*)&a_s[n * 4] = make_float4(ps0, ps1, ps2, ps3);
    *(float4*)&a_d[n * 4] = make_float4(pd0, pd1, pd2, pd3);
  }
}

// ---------------------------------------------------------------------------
// Layer-1 softmax + aggregate h (176-dim) per head -> aggh[(ln*4+h)*176+k].
// Wave-per-node, zero barriers. Nodes [n0, n0+nM).
// ---------------------------------------------------------------------------
__global__ __launch_bounds__(256) void agg1h_kernel(
    const float* __restrict__ h, const float* __restrict__ a_src,
    const float* __restrict__ a_dst, const int* __restrict__ indptr,
    const int* __restrict__ srcs, float* __restrict__ aggh,
    int n0, int nM) {
  int lane = threadIdx.x & 63;
  int ln = blockIdx.x * 4 + (threadIdx.x >> 6);
  if (ln >= nM) return;
  int n = n0 + ln;
  int beg = indptr[n], end = indptr[n + 1];
  int deg = end - beg;
  float4 ad = *(const float4*)&a_dst[n * 4];
  bool l48 = lane < 48;
  float acc[4][3] = {};

  auto body = [&](int s, float al0, float al1, float al2, float al3) {
    const float* r = h + (size_t)s * IN_DIM;
    float v0 = r[lane];
    float v1 = r[64 + lane];
    float v2 = l48 ? r[128 + lane] : 0.f;
    acc[0][0] += al0 * v0; acc[0][1] += al0 * v1; acc[0][2] += al0 * v2;
    acc[1][0] += al1 * v0; acc[1][1] += al1 * v1; acc[1][2] += al1 * v2;
    acc[2][0] += al2 * v0; acc[2][1] += al2 * v1; acc[2][2] += al2 * v2;
    acc[3][0] += al3 * v0; acc[3][1] += al3 * v1; acc[3][2] += al3 * v2;
  };

  if (deg <= 64) {
    int j = beg + lane;
    int s = 0;
    float e0 = -INFINITY, e1 = -INFINITY, e2 = -INFINITY, e3 = -INFINITY;
    if (j < end) {
      s = srcs[j];
      float4 as = *(const float4*)&a_src[s * 4];
      e0 = leaky(as.x + ad.x); e1 = leaky(as.y + ad.y);
      e2 = leaky(as.z + ad.z); e3 = leaky(as.w + ad.w);
    }
    float m0 = e0, m1 = e1, m2 = e2, m3 = e3;
    for (int off = 1; off < 64; off <<= 1) {
      m0 = fmaxf(m0, __shfl_xor(m0, off)); m1 = fmaxf(m1, __shfl_xor(m1, off));
      m2 = fmaxf(m2, __shfl_xor(m2, off)); m3 = fmaxf(m3, __shfl_xor(m3, off));
    }
    float x0 = (j < end) ? expf(e0 - m0) : 0.f;
    float x1 = (j < end) ? expf(e1 - m1) : 0.f;
    float x2 = (j < end) ? expf(e2 - m2) : 0.f;
    float x3 = (j < end) ? expf(e3 - m3) : 0.f;
    float d0 = x0, d1 = x1, d2 = x2, d3 = x3;
    for (int off = 1; off < 64; off <<= 1) {
      d0 += __shfl_xor(d0, off); d1 += __shfl_xor(d1, off);
      d2 += __shfl_xor(d2, off); d3 += __shfl_xor(d3, off);
    }
    float al0 = x0 / (d0 + 1e-16f), al1 = x1 / (d1 + 1e-16f);
    float al2 = x2 / (d2 + 1e-16f), al3 = x3 / (d3 + 1e-16f);
    int jj = 0;
    for (; jj + 2 <= deg; jj += 2) {
      int sa = readlane_i(s, jj), sb = readlane_i(s, jj + 1);
      float a0 = readlane_f(al0, jj), a1 = readlane_f(al1, jj);
      float a2 = readlane_f(al2, jj), a3 = readlane_f(al3, jj);
      float b0 = readlane_f(al0, jj + 1), b1 = readlane_f(al1, jj + 1);
      float b2 = readlane_f(al2, jj + 1), b3 = readlane_f(al3, jj + 1);
      body(sa, a0, a1, a2, a3);
      body(sb, b0, b1, b2, b3);
    }
    if (jj < deg) {
      int sa = readlane_i(s, jj);
      body(sa, readlane_f(al0, jj), readlane_f(al1, jj),
           readlane_f(al2, jj), readlane_f(al3, jj));
    }
  } else {
    float m0 = -INFINITY, m1 = -INFINITY, m2 = -INFINITY, m3 = -INFINITY;
    for (int j0 = beg; j0 < end; j0 += 64) {
      int j = j0 + lane;
      if (j < end) {
        int s = srcs[j];
        float4 as = *(const float4*)&a_src[s * 4];
        m0 = fmaxf(m0, leaky(as.x + ad.x)); m1 = fmaxf(m1, leaky(as.y + ad.y));
        m2 = fmaxf(m2, leaky(as.z + ad.z)); m3 = fmaxf(m3, leaky(as.w + ad.w));
      }
    }
    for (int off = 1; off < 64; off <<= 1) {
      m0 = fmaxf(m0, __shfl_xor(m0, off)); m1 = fmaxf(m1, __shfl_xor(m1, off));
      m2 = fmaxf(m2, __shfl_xor(m2, off)); m3 = fmaxf(m3, __shfl_xor(m3, off));
    }
    float d0 = 0.f, d1 = 0.f, d2 = 0.f, d3 = 0.f;
    for (int j0 = beg; j0 < end; j0 += 64) {
      int j = j0 + lane;
      if (j < end) {
        int s = srcs[j];
        float4 as = *(const float4*)&a_src[s * 4];
        d0 += expf(leaky(as.x + ad.x) - m0); d1 += expf(leaky(as.y + ad.y) - m1);
        d2 += expf(leaky(as.z + ad.z) - m2); d3 += expf(leaky(as.w + ad.w) - m3);
      }
    }
    for (int off = 1; off < 64; off <<= 1) {
      d0 += __shfl_xor(d0, off); d1 += __shfl_xor(d1, off);
      d2 += __shfl_xor(d2, off); d3 += __shfl_xor(d3, off);
    }
    float r0 = 1.f / (d0 + 1e-16f), r1 = 1.f / (d1 + 1e-16f);
    float r2 = 1.f / (d2 + 1e-16f), r3 = 1.f / (d3 + 1e-16f);
    for (int j0 = beg; j0 < end; j0 += 64) {
      int jn = min(64, end - j0);
      int j = j0 + lane;
      int s = 0;
      float al0 = 0.f, al1 = 0.f, al2 = 0.f, al3 = 0.f;
      if (j < end) {
        s = srcs[j];
        float4 as = *(const float4*)&a_src[s * 4];
        al0 = expf(leaky(as.x + ad.x) - m0) * r0;
        al1 = expf(leaky(as.y + ad.y) - m1) * r1;
        al2 = expf(leaky(as.z + ad.z) - m2) * r2;
        al3 = expf(leaky(as.w + ad.w) - m3) * r3;
      }
      for (int jj = 0; jj < jn; ++jj) {
        body(readlane_i(s, jj), readlane_f(al0, jj), readlane_f(al1, jj),
             readlane_f(al2, jj), readlane_f(al3, jj));
      }
    }
  }

  size_t base = (size_t)ln * (4 * IN_DIM);
#pragma unroll
  for (int hh = 0; hh < 4; ++hh) {
    aggh[base + hh * IN_DIM + lane] = acc[hh][0];
    aggh[base + hh * IN_DIM + 64 + lane] = acc[hh][1];
    if (l48) aggh[base + hh * IN_DIM + 128 + lane] = acc[hh][2];
  }
}

// ---------------------------------------------------------------------------
// Head-GEMM: out1[n0+r, h*128+c] = ELU( aggh_h[r,:]@W1[:,h*128+c] + b1 ).
// BM=128, BN=128, BK=8, TM=TN=8, grid (1, ceil(M/128), 4 heads).
// ---------------------------------------------------------------------------
__global__ __launch_bounds__(256) void gemm_head_kernel(
    const float* __restrict__ aggh, const float* __restrict__ W1,
    const float* __restrict__ b1, float* __restrict__ out1,
    int M, int n0) {
  const int BM = 128, BN = 128, BK = 8, TM = 8, TN = 8;
  __shared__ float As[BK][BM + 4];
  __shared__ float Bs[BK][BN];
  int tid = threadIdx.x;
  int hh = blockIdx.z;
  int tr = tid / 16, tc = tid % 16;
  int row0 = blockIdx.y * BM;
  float acc[TM][TN] = {};
  for (int k0 = 0; k0 < IN_DIM; k0 += BK) {
    {
      int i = tid;  // 256 = BM*BK/4
      int r = i >> 1, kq = (i & 1) * 4;
      int gr = row0 + r;
      float4 v = make_float4(0.f, 0.f, 0.f, 0.f);
      if (gr < M) v = *(const float4*)&aggh[((size_t)gr * 4 + hh) * IN_DIM + k0 + kq];
      As[kq + 0][r] = v.x; As[kq + 1][r] = v.y;
      As[kq + 2][r] = v.z; As[kq + 3][r] = v.w;
    }
    {
      int i = tid;  // 256 = BK*BN/4
      int kk = i >> 5, cq = (i & 31) * 4;
      *(float4*)&Bs[kk][cq] = *(const float4*)&W1[(size_t)(k0 + kk) * 512 + hh * 128 + cq];
    }
    __syncthreads();
#pragma unroll
    for (int kk = 0; kk < BK; ++kk) {
      float a[TM], b[TN];
#pragma unroll
      for (int i = 0; i < TM; i += 4)
        *(float4*)&a[i] = *(const float4*)&As[kk][tr * TM + i];
#pragma unroll
      for (int j = 0; j < TN; j += 4)
        *(float4*)&b[j] = *(const float4*)&Bs[kk][tc * TN + j];
#pragma unroll
      for (int i = 0; i < TM; ++i)
#pragma unroll
        for (int j = 0; j < TN; ++j) acc[i][j] += a[i] * b[j];
    }
    __syncthreads();
  }
  for (int i = 0; i < TM; ++i) {
    int gr = row0 + tr * TM + i;
    if (gr >= M) continue;
    float4 o0, o1;
    float* po = (float*)&o0;
#pragma unroll
    for (int j = 0; j < TN; ++j) {
      float v = acc[i][j] + b1[hh * 128 + tc * TN + j];
      ((float*)&o0)[0];  // no-op to appease unroll
      po = (j < 4) ? (float*)&o0 : (float*)&o1;
      po[j & 3] = elu(v);
    }
    float* dst = &out1[(size_t)(n0 + gr) * 512 + hh * 128 + tc * TN];
    *(float4*)&dst[0] = o0;
    *(float4*)&dst[4] = o1;
  }
}

// ---------------------------------------------------------------------------
// fp32 GEMM: C[M,N] = A[M,K] @ B[K,N]. 256 threads (16x16), BK=8.
// ---------------------------------------------------------------------------
template <int BM, int BN, int TM, int TN>
__global__ __launch_bounds__(256) void gemm_kernel(const float* __restrict__ A,
                                                   const float* __restrict__ B,
                                                   float* __restrict__ C,
                                                   int M, int N, int K) {
  const int BK = 8;
  __shared__ float As[BK][BM + 4];
  __shared__ float Bs[BK][BN];
  int tid = threadIdx.x;
  int tr = tid / 16, tc = tid % 16;
  int row0 = blockIdx.y * BM, col0 = blockIdx.x * BN;
  float acc[TM][TN] = {};
  for (int k0 = 0; k0 < K; k0 += BK) {
    for (int i = tid; i < BM * BK / 4; i += 256) {
      int r = i / (BK / 4), kq = (i % (BK / 4)) * 4;
      int gr = row0 + r;
      float4 v = make_float4(0.f, 0.f, 0.f, 0.f);
      if (gr < M) v = *(const float4*)&A[(size_t)gr * K + k0 + kq];
      As[kq + 0][r] = v.x; As[kq + 1][r] = v.y;
      As[kq + 2][r] = v.z; As[kq + 3][r] = v.w;
    }
    for (int i = tid; i < BK * BN / 4; i += 256) {
      int kk = i / (BN / 4), cq = (i % (BN / 4)) * 4;
      *(float4*)&Bs[kk][cq] = *(const float4*)&B[(size_t)(k0 + kk) * N + col0 + cq];
    }
    __syncthreads();
#pragma unroll
    for (int kk = 0; kk < BK; ++kk) {
      float a[TM], b[TN];
#pragma unroll
      for (int i = 0; i < TM; i += 4)
        *(float4*)&a[i] = *(const float4*)&As[kk][tr * TM + i];
#pragma unroll
      for (int j = 0; j < TN; j += 4)
        *(float4*)&b[j] = *(const float4*)&Bs[kk][tc * TN + j];
#pragma unroll
      for (int i = 0; i < TM; ++i)
#pragma unroll
        for (int j = 0; j < TN; ++j) acc[i][j] += a[i] * b[j];
    }
    __syncthreads();
  }
  for (int i = 0; i < TM; ++i) {
    int gr = row0 + tr * TM + i;
    if (gr >= M) continue;
#pragma unroll
    for (int j = 0; j < TN; j += 4)
      *(float4*)&C[(size_t)gr * N + col0 + tc * TN + j] = *(float4*)&acc[i][j];
  }
}

// ---------------------------------------------------------------------------
// Layer-2 attention logits (H=1, C=128), wave-per-node.
// ---------------------------------------------------------------------------
__global__ __launch_bounds__(256) void att2_kernel(
    const float* __restrict__ xw, const float* __restrict__ att_s,
    const float* __restrict__ att_d, float* __restrict__ a_s,
    float* __restrict__ a_d) {
  int lane = threadIdx.x & 63;
  int n = blockIdx.x * 4 + (threadIdx.x >> 6);
  if (n >= N_NODES) return;
  const float* r = xw + (size_t)n * HID;
  float2 v = *(const float2*)&r[lane * 2];
  float2 as = *(const float2*)&att_s[lane * 2];
  float2 ad = *(const float2*)&att_d[lane * 2];
  float ps = v.x * as.x + v.y * as.y;
  float pd = v.x * ad.x + v.y * ad.y;
  for (int off = 1; off < 64; off <<= 1) {
    ps += __shfl_xor(ps, off);
    pd += __shfl_xor(pd, off);
  }
  if (lane == 0) { a_s[n] = ps; a_d[n] = pd; }
}

// ---------------------------------------------------------------------------
// Layer-2 aggregate: H=1, C=128. Half-wave per edge, float4 loads.
// ---------------------------------------------------------------------------
__global__ __launch_bounds__(256) void agg2_kernel(
    const float* __restrict__ xw, const float* __restrict__ a_src,
    const float* __restrict__ a_dst, const int* __restrict__ indptr,
    const int* __restrict__ srcs, const float* __restrict__ bias,
    float* __restrict__ out) {
  int lane = threadIdx.x & 63;
  int n = blockIdx.x * 4 + (threadIdx.x >> 6);
  if (n >= N_NODES) return;
  int beg = indptr[n], end = indptr[n + 1];
  int deg = end - beg;
  float adn = a_dst[n];
  int half = lane >> 5, l32 = lane & 31;
  float4 acc = make_float4(0.f, 0.f, 0.f, 0.f);

  auto pairs = [&](int s, float al, int jn) {
    int jj = 0;
    for (; jj + 2 <= jn; jj += 2) {
      int sa = readlane_i(s, jj), sb = readlane_i(s, jj + 1);
      float aa = readlane_f(al, jj), ab = readlane_f(al, jj + 1);
      int sh = half ? sb : sa;
      float ah = half ? ab : aa;
      float4 v = *(const float4*)&xw[(size_t)sh * HID + l32 * 4];
      acc.x += ah * v.x; acc.y += ah * v.y; acc.z += ah * v.z; acc.w += ah * v.w;
    }
    if (jj < jn) {
      int sa = readlane_i(s, jj);
      float ah = half ? 0.f : readlane_f(al, jj);
      float4 v = *(const float4*)&xw[(size_t)sa * HID + l32 * 4];
      acc.x += ah * v.x; acc.y += ah * v.y; acc.z += ah * v.z; acc.w += ah * v.w;
    }
  };

  if (deg <= 64) {
    int j = beg + lane;
    int s = 0;
    float e = -INFINITY;
    if (j < end) { s = srcs[j]; e = leaky(a_src[s] + adn); }
    float m = e;
    for (int off = 1; off < 64; off <<= 1) m = fmaxf(m, __shfl_xor(m, off));
    float x = (j < end) ? expf(e - m) : 0.f;
    float d = x;
    for (int off = 1; off < 64; off <<= 1) d += __shfl_xor(d, off);
    float al = x / (d + 1e-16f);
    pairs(s, al, deg);
  } else {
    float m = -INFINITY;
    for (int j0 = beg; j0 < end; j0 += 64) {
      int j = j0 + lane;
      if (j < end) m = fmaxf(m, leaky(a_src[srcs[j]] + adn));
    }
    for (int off = 1; off < 64; off <<= 1) m = fmaxf(m, __shfl_xor(m, off));
    float d = 0.f;
    for (int j0 = beg; j0 < end; j0 += 64) {
      int j = j0 + lane;
      if (j < end) d += expf(leaky(a_src[srcs[j]] + adn) - m);
    }
    for (int off = 1; off < 64; off <<= 1) d += __shfl_xor(d, off);
    float rd = 1.f / (d + 1e-16f);
    for (int j0 = beg; j0 < end; j0 += 64) {
      int jn = min(64, end - j0);
      int j = j0 + lane;
      int s = 0;
      float al = 0.f;
      if (j < end) {
        s = srcs[j];
        al = expf(leaky(a_src[s] + adn) - m) * rd;
      }
      pairs(s, al, jn);
    }
  }

  // combine halves: lanes i and i+32 hold partial sums of the same columns
  acc.x += __shfl_xor(acc.x, 32); acc.y += __shfl_xor(acc.y, 32);
  acc.z += __shfl_xor(acc.z, 32); acc.w += __shfl_xor(acc.w, 32);
  if (half == 0) {
    float4 b = *(const float4*)&bias[l32 * 4];
    float4 o;
    o.x = elu(acc.x + b.x); o.y = elu(acc.y + b.y);
    o.z = elu(acc.z + b.z); o.w = elu(acc.w + b.w);
    *(float4*)&out[(size_t)n * HID + l32 * 4] = o;
  }
}

// ---------------------------------------------------------------------------
// Graph ranges (batch sorted), max-pool per graph, classifier head.
// ---------------------------------------------------------------------------
__global__ void gstart_kernel(const int* __restrict__ batch,
                              int* __restrict__ gstarts, int N, int G) {
  int t = threadIdx.x;
  if (t > G) return;
  int lo = 0, hi = N;
  while (lo < hi) {
    int mid = (lo + hi) >> 1;
    if (batch[mid] < t) lo = mid + 1; else hi = mid;
  }
  gstarts[t] = lo;
}

__global__ __launch_bounds__(HID) void pool_kernel(const float* __restrict__ out2,
                                                   const int* __restrict__ gstarts,
                                                   float* __restrict__ pooled) {
  int g = blockIdx.x, t = threadIdx.x;
  int beg = gstarts[g], end = gstarts[g + 1];
  float m = -INFINITY;
  for (int n = beg; n < end; ++n) m = fmaxf(m, out2[n * HID + t]);
  pooled[g * HID + t] = m;
}

__global__ __launch_bounds__(HID) void cls_kernel(const float* __restrict__ pooled,
                                                  const float* __restrict__ w1,
                                                  const float* __restrict__ b1,
                                                  const float* __restrict__ w2,
                                                  const float* __restrict__ b2,
                                                  float* __restrict__ out) {
  int g = blockIdx.x, t = threadIdx.x;
  __shared__ float sp[HID], sh1[HID / 2];
  sp[t] = pooled[g * HID + t];
  __syncthreads();
  if (t < HID / 2) {
    float s = b1[t];
    for (int k = 0; k < HID; ++k) s += sp[k] * w1[k * (HID / 2) + t];
    sh1[t] = fmaxf(s, 0.f);
  }
  __syncthreads();
  if (t < 2) {
    float o = b2[t];
    for (int k = 0; k < HID / 2; ++k) o += sh1[k] * w2[k * 2 + t];
    out[g * 2 + t] = o;
  }
}

// ---------------------------------------------------------------------------
extern "C" void kernel_launch(void* const* d_in, const int* in_sizes, int n_in,
                              void* d_out, int out_size, void* d_ws, size_t ws_size,
                              hipStream_t stream) {
  const float* x_scalar = (const float*)d_in[0];
  const int* x_opcode   = (const int*)d_in[1];
  const int* x_source   = (const int*)d_in[2];
  const int* x_sink     = (const int*)d_in[3];
  const int* x_string   = (const int*)d_in[4];
  const int* x_payload  = (const int*)d_in[5];
  const int* edge_index = (const int*)d_in[6];
  const int* batch      = (const int*)d_in[7];
  const float* emb_opcode = (const float*)d_in[8];
  const float* emb_source = (const float*)d_in[9];
  const float* emb_sink   = (const float*)d_in[10];
  const float* emb_string = (const float*)d_in[11];
  const float* emb_payload= (const float*)d_in[12];
  const float* ln_gamma = (const float*)d_in[13];
  const float* ln_beta  = (const float*)d_in[14];
  const float* W1       = (const float*)d_in[15];
  const float* att_src1 = (const float*)d_in[16];
  const float* att_dst1 = (const float*)d_in[17];
  const float* b1       = (const float*)d_in[18];
  const float* W2       = (const float*)d_in[19];
  const float* att_src2 = (const float*)d_in[20];
  const float* att_dst2 = (const float*)d_in[21];
  const float* b2       = (const float*)d_in[22];
  const float* cls_w1   = (const float*)d_in[23];
  const float* cls_b1   = (const float*)d_in[24];
  const float* cls_w2   = (const float*)d_in[25];
  const float* cls_b2   = (const float*)d_in[26];

  // Workspace layout (~96 MB).
  float* h      = (float*)d_ws;                       // [N,176]
  float* aggh   = h + (size_t)N_NODES * IN_DIM;       // [CHUNK*704]; later xw2 [N,128]
  float* out1   = aggh + (size_t)CHUNK * 4 * IN_DIM;  // [N,512]
  float* out2   = out1 + (size_t)N_NODES * 512;       // [N,128]
  float* a1s    = out2 + (size_t)N_NODES * HID;       // [N,4]
  float* a1d    = a1s + N_NODES * 4;
  float* a2s    = a1d + N_NODES * 4;                  // [N]
  float* a2d    = a2s + N_NODES;
  float* was4   = a2d + N_NODES;                      // [176*4]
  float* wad4   = was4 + IN_DIM * 4;                  // [176*4]
  float* pooled = wad4 + IN_DIM * 4;                  // [G,128]
  int* indptr = (int*)(pooled + N_GRAPHS * HID);      // [N+1]
  int* cnt    = indptr + (N_NODES + 1);               // [N]
  int* cursor = cnt + N_NODES;                        // [N]
  int* srcs   = cursor + N_NODES;                     // [E+N]
  int* gstarts= srcs + TOT_EDGES;                     // [G+1]
  float* xw2  = aggh;                                 // alias (aggh dead after head GEMMs)

  hipMemsetAsync(cnt, 0, 2 * N_NODES * sizeof(int), stream);

  feats_ln_kernel<<<N_NODES, 192, 0, stream>>>(
      x_scalar, x_opcode, x_source, x_sink, x_string, x_payload,
      emb_opcode, emb_source, emb_sink, emb_string, emb_payload,
      ln_gamma, ln_beta, h);

  int nthreads = TOT_EDGES;
  count_kernel<<<(nthreads + 255) / 256, 256, 0, stream>>>(edge_index, cnt, N_EDGES, N_NODES);
  prefix_kernel<<<1, 256, 0, stream>>>(cnt, indptr, N_NODES, TOT_EDGES);
  scatter_kernel<<<(nthreads + 255) / 256, 256, 0, stream>>>(edge_index, indptr, cursor, srcs, N_EDGES, N_NODES);

  wasd_kernel<<<1, 256, 0, stream>>>(W1, att_src1, att_dst1, was4, wad4);

  const int NB4 = (N_NODES + 3) / 4;
  att1h_kernel<<<NB4, 256, 0, stream>>>(h, was4, wad4, a1s, a1d);

  // Layer 1 in two node-chunks: aggregate h per head, then head-GEMM (+bias+ELU).
  for (int c = 0; c < 2; ++c) {
    int n0 = c * CHUNK;
    int nM = min(CHUNK, N_NODES - n0);
    agg1h_kernel<<<(nM + 3) / 4, 256, 0, stream>>>(h, a1s, a1d, indptr, srcs, aggh, n0, nM);
    gemm_head_kernel<<<dim3(1, (nM + 127) / 128, 4), 256, 0, stream>>>(
        aggh, W1, b1, out1, nM, n0);
  }

  // GEMM2: [N,512] @ [512,128] -> xw2
  gemm_kernel<64, 128, 4, 8><<<dim3(1, (N_NODES + 63) / 64), 256, 0, stream>>>(
      out1, W2, xw2, N_NODES, HID, 512);
  att2_kernel<<<NB4, 256, 0, stream>>>(xw2, att_src2, att_dst2, a2s, a2d);
  agg2_kernel<<<NB4, 256, 0, stream>>>(xw2, a2s, a2d, indptr, srcs, b2, out2);

  gstart_kernel<<<1, 128, 0, stream>>>(batch, gstarts, N_NODES, N_GRAPHS);
  pool_kernel<<<N_GRAPHS, HID, 0, stream>>>(out2, gstarts, pooled);
  cls_kernel<<<N_GRAPHS, HID, 0, stream>>>(pooled, cls_w1, cls_b1, cls_w2, cls_b2, (float*)d_out);
}